// Round 1
// baseline (7988.571 us; speedup 1.0000x reference)
//
#include <hip/hip_runtime.h>

#define SEQ 2048
#define DMODEL 1024
#define DINNER 2048
#define DSTATE 16
#define DTRANK 64
#define NLAYER 8
#define VOCAB 32000

typedef float f32x4 __attribute__((ext_vector_type(4)));
typedef short bf16x8 __attribute__((ext_vector_type(8)));

__device__ __forceinline__ ushort f2bf(float f) {
  union { float f; unsigned u; } v; v.f = f;
  unsigned r = v.u + 0x7fffu + ((v.u >> 16) & 1u);
  return (ushort)(r >> 16);
}

__device__ __forceinline__ void lds_load16(const void* g, void* l) {
  __builtin_amdgcn_global_load_lds(
      (const __attribute__((address_space(1))) void*)g,
      (__attribute__((address_space(3))) void*)l, 16, 0, 0);
}

// ---------------- bf16 MFMA GEMM:  C[M,N] = A[M,K] @ B[N,K]^T (+ addsrc) ----
// 128x128 tile, BK=64, 4 waves (2x2), 16x16x32 MFMA, global_load_lds staging.
__global__ __launch_bounds__(256) void gemm_bt_bf16(
    const ushort* __restrict__ A, const ushort* __restrict__ B,
    const float* __restrict__ addsrc, float* __restrict__ C,
    int M, int N, int K)
{
  __shared__ __align__(16) ushort As[128 * 64];
  __shared__ __align__(16) ushort Bs[128 * 64];
  const int tid = threadIdx.x;
  const int lane = tid & 63;
  const int wave = tid >> 6;
  const int wr = wave >> 1, wc = wave & 1;
  const int bm = blockIdx.x * 128;
  const int bn = blockIdx.y * 128;
  const int rr = lane & 15, kq = lane >> 4;

  f32x4 acc[4][4];
#pragma unroll
  for (int m = 0; m < 4; ++m)
#pragma unroll
    for (int n = 0; n < 4; ++n) acc[m][n] = (f32x4){0.f, 0.f, 0.f, 0.f};

  for (int kt = 0; kt < K; kt += 64) {
#pragma unroll
    for (int i = 0; i < 4; ++i) {
      int fb = i * 256 + tid;          // 0..1023, covers 128x64 in 16B chunks
      int row = fb >> 3, cb = fb & 7;
      lds_load16(A + (size_t)(bm + row) * K + kt + cb * 8, (void*)(As + (size_t)fb * 8));
      lds_load16(B + (size_t)(bn + row) * K + kt + cb * 8, (void*)(Bs + (size_t)fb * 8));
    }
    __syncthreads();
#pragma unroll
    for (int ks = 0; ks < 2; ++ks) {
      bf16x8 af[4], bfr[4];
      const int koff = ks * 32 + kq * 8;
#pragma unroll
      for (int m = 0; m < 4; ++m)
        af[m] = *(const bf16x8*)&As[(wr * 64 + m * 16 + rr) * 64 + koff];
#pragma unroll
      for (int n = 0; n < 4; ++n)
        bfr[n] = *(const bf16x8*)&Bs[(wc * 64 + n * 16 + rr) * 64 + koff];
#pragma unroll
      for (int m = 0; m < 4; ++m)
#pragma unroll
        for (int n = 0; n < 4; ++n)
          acc[m][n] = __builtin_amdgcn_mfma_f32_16x16x32_bf16(af[m], bfr[n], acc[m][n], 0, 0, 0);
    }
    __syncthreads();
  }
  // C/D layout (verified m89/m91): col = lane&15, row = (lane>>4)*4 + reg
#pragma unroll
  for (int m = 0; m < 4; ++m) {
    const int r0 = bm + wr * 64 + m * 16 + kq * 4;
#pragma unroll
    for (int n = 0; n < 4; ++n) {
      const int cc = bn + wc * 64 + n * 16 + rr;
#pragma unroll
      for (int j = 0; j < 4; ++j) {
        size_t idx = (size_t)(r0 + j) * N + cc;
        float v = acc[m][n][j];
        if (addsrc) v += addsrc[idx];
        C[idx] = v;
      }
    }
  }
}

// ---------------- f32 small GEMM: C[M,N] = A[M,K(lda)] @ W[N,K(ldw)]^T ------
// 64x64 tile, pad stride 65 (2-way LDS conflicts only). act=1: softplus(+bias)
__global__ __launch_bounds__(256) void smallgemm_f32(
    const float* __restrict__ A, int lda,
    const float* __restrict__ W, int ldw,
    float* __restrict__ C, int ldc,
    const float* __restrict__ bias,
    int M, int N, int K, int act)
{
  __shared__ float As[64][65];
  __shared__ float Ws[64][65];
  const int t = threadIdx.x;
  const int bm = blockIdx.x * 64, bn = blockIdx.y * 64;
  const int r0 = (t >> 4) * 4;
  const int c0 = (t & 15) * 4;
  float acc[4][4] = {};

  for (int kt = 0; kt < K; kt += 64) {
#pragma unroll
    for (int i = 0; i < 16; ++i) {
      int idx = i * 256 + t;
      int r = idx >> 6, c = idx & 63;
      As[r][c] = A[(size_t)(bm + r) * lda + kt + c];
      int wrow = bn + r;
      Ws[r][c] = (wrow < N) ? W[(size_t)wrow * ldw + kt + c] : 0.f;
    }
    __syncthreads();
#pragma unroll 8
    for (int kk = 0; kk < 64; ++kk) {
      float a0 = As[r0][kk], a1 = As[r0 + 1][kk], a2 = As[r0 + 2][kk], a3 = As[r0 + 3][kk];
      float w0 = Ws[c0][kk], w1 = Ws[c0 + 1][kk], w2 = Ws[c0 + 2][kk], w3 = Ws[c0 + 3][kk];
      acc[0][0] += a0 * w0; acc[0][1] += a0 * w1; acc[0][2] += a0 * w2; acc[0][3] += a0 * w3;
      acc[1][0] += a1 * w0; acc[1][1] += a1 * w1; acc[1][2] += a1 * w2; acc[1][3] += a1 * w3;
      acc[2][0] += a2 * w0; acc[2][1] += a2 * w1; acc[2][2] += a2 * w2; acc[2][3] += a2 * w3;
      acc[3][0] += a3 * w0; acc[3][1] += a3 * w1; acc[3][2] += a3 * w2; acc[3][3] += a3 * w3;
    }
    __syncthreads();
  }
#pragma unroll
  for (int i = 0; i < 4; ++i)
#pragma unroll
    for (int j = 0; j < 4; ++j) {
      int cc = bn + c0 + j;
      if (cc < N) {
        float v = acc[i][j];
        if (bias) v += bias[cc];
        if (act == 1) v = (v > 20.f) ? v : log1pf(expf(v));  // softplus
        C[(size_t)(bm + r0 + i) * ldc + cc] = v;
      }
    }
}

// ---------------- embedding gather ------------------------------------------
__global__ __launch_bounds__(256) void gather_kernel(
    const int* __restrict__ ids, const float* __restrict__ embed, float* __restrict__ x)
{
  int row = blockIdx.x;
  int id = ids[row];
  ((float4*)x)[(size_t)row * (DMODEL / 4) + threadIdx.x] =
      ((const float4*)(embed + (size_t)id * DMODEL))[threadIdx.x];
}

// ---------------- RMSNorm (no scale) -> bf16 --------------------------------
__global__ __launch_bounds__(256) void rmsnorm_kernel(
    const float* __restrict__ x, ushort* __restrict__ xnb)
{
  int row = blockIdx.x;
  float4 v = ((const float4*)(x + (size_t)row * DMODEL))[threadIdx.x];
  float s = v.x * v.x + v.y * v.y + v.z * v.z + v.w * v.w;
#pragma unroll
  for (int o = 32; o > 0; o >>= 1) s += __shfl_down(s, o);
  __shared__ float ws[4];
  if ((threadIdx.x & 63) == 0) ws[threadIdx.x >> 6] = s;
  __syncthreads();
  float tot = ws[0] + ws[1] + ws[2] + ws[3];
  float sc = rsqrtf(tot * (1.0f / DMODEL) + 1e-6f);
  ushort4 o4 = {f2bf(v.x * sc), f2bf(v.y * sc), f2bf(v.z * sc), f2bf(v.w * sc)};
  ((ushort4*)xnb)[(size_t)row * (DMODEL / 4) + threadIdx.x] = o4;
}

// ---------------- causal depthwise conv (K=4) + SiLU ------------------------
__global__ __launch_bounds__(256) void conv_silu_kernel(
    const float* __restrict__ u0, const float* __restrict__ Wconv, float* __restrict__ u)
{
  int idx = blockIdx.x * 256 + threadIdx.x;  // over SEQ * DINNER/4
  int d4 = idx & (DINNER / 4 - 1);
  int l = idx >> 9;  // DINNER/4 == 512
  int d0 = d4 * 4;
  float wt[4][4];
#pragma unroll
  for (int j = 0; j < 4; ++j) {
    float4 tv = *(const float4*)&Wconv[(d0 + j) * 4];
    wt[j][0] = tv.x; wt[j][1] = tv.y; wt[j][2] = tv.z; wt[j][3] = tv.w;
  }
  float a[4] = {0.f, 0.f, 0.f, 0.f};
#pragma unroll
  for (int k = 0; k < 4; ++k) {
    int ls = l - 3 + k;
    if (ls >= 0) {
      float4 uv = *(const float4*)&u0[(size_t)ls * DINNER + d0];
      a[0] += uv.x * wt[0][k];
      a[1] += uv.y * wt[1][k];
      a[2] += uv.z * wt[2][k];
      a[3] += uv.w * wt[3][k];
    }
  }
  float4 r;
  r.x = a[0] / (1.f + expf(-a[0]));
  r.y = a[1] / (1.f + expf(-a[1]));
  r.z = a[2] / (1.f + expf(-a[2]));
  r.w = a[3] / (1.f + expf(-a[3]));
  *(float4*)&u[(size_t)l * DINNER + d0] = r;
}

// ---------------- selective scan (bilinear discretization) ------------------
// thread = (channel dl, state n); 16 channels/block; shfl-reduce over 16 states
__global__ __launch_bounds__(256) void scan_kernel(
    const float* __restrict__ dt, const float* __restrict__ u,
    const float* __restrict__ bcdt,  // [SEQ][96]: B=0..15, C=16..31
    const float* __restrict__ logA, const float* __restrict__ Dp,
    float* __restrict__ y)
{
  const int tid = threadIdx.x;
  const int n = tid & 15, dl = tid >> 4;
  const int dbase = blockIdx.x * 16;
  const int d = dbase + dl;
  const float Aval = -expf(logA[d * DSTATE + n]);
  const float Dpv = Dp[d];
  __shared__ float sB[64][16], sC[64][16], sdt[64][16], su[64][16];
  float h = 0.f;
  for (int t0 = 0; t0 < SEQ; t0 += 64) {
    for (int i = tid; i < 64 * 16; i += 256) {
      int tt = i >> 4, j = i & 15;
      sB[tt][j] = bcdt[(size_t)(t0 + tt) * 96 + j];
      sC[tt][j] = bcdt[(size_t)(t0 + tt) * 96 + 16 + j];
      sdt[tt][j] = dt[(size_t)(t0 + tt) * DINNER + dbase + j];
      su[tt][j] = u[(size_t)(t0 + tt) * DINNER + dbase + j];
    }
    __syncthreads();
    for (int i = 0; i < 64; ++i) {
      float dtv = sdt[i][dl], uv = su[i][dl];
      float Bv = sB[i][n], Cv = sC[i][n];
      float dtA = dtv * Aval;
      float den = 1.f - 0.5f * dtA;
      float rinv = 1.f / den;
      float dA = (1.f + 0.5f * dtA) * rinv;
      float dB = dtv * Bv * rinv;
      h = dA * h + dB * uv;
      float p = h * Cv;
      p += __shfl_xor(p, 1);
      p += __shfl_xor(p, 2);
      p += __shfl_xor(p, 4);
      p += __shfl_xor(p, 8);
      if (n == 0) y[(size_t)(t0 + i) * DINNER + d] = p + uv * Dpv;
    }
    __syncthreads();
  }
}

// ---------------- y2 = y * silu(res) -> bf16 --------------------------------
__global__ __launch_bounds__(256) void ymul_cast_kernel(
    const float* __restrict__ y, const float* __restrict__ res, ushort* __restrict__ y2b)
{
  size_t i = (size_t)blockIdx.x * 256 + threadIdx.x;  // over SEQ*DINNER/4
  float4 yv = ((const float4*)y)[i];
  float4 rv = ((const float4*)res)[i];
  float s0 = rv.x / (1.f + expf(-rv.x));
  float s1 = rv.y / (1.f + expf(-rv.y));
  float s2 = rv.z / (1.f + expf(-rv.z));
  float s3 = rv.w / (1.f + expf(-rv.w));
  ushort4 o = {f2bf(yv.x * s0), f2bf(yv.y * s1), f2bf(yv.z * s2), f2bf(yv.w * s3)};
  ((ushort4*)y2b)[i] = o;
}

// ---------------- f32 -> bf16 cast ------------------------------------------
__global__ __launch_bounds__(256) void cast_bf16_kernel(
    const float* __restrict__ in, ushort* __restrict__ out, size_t n4)
{
  size_t i = (size_t)blockIdx.x * 256 + threadIdx.x;
  if (i >= n4) return;
  float4 v = ((const float4*)in)[i];
  ushort4 o = {f2bf(v.x), f2bf(v.y), f2bf(v.z), f2bf(v.w)};
  ((ushort4*)out)[i] = o;
}

// ---------------- concat WB|WC|Wdt1 -> [L][96][DINNER] ----------------------
__global__ __launch_bounds__(256) void concat_wbcdt_kernel(
    const float* __restrict__ WB, const float* __restrict__ WC,
    const float* __restrict__ Wdt1, float* __restrict__ out)
{
  size_t idx = (size_t)blockIdx.x * 256 + threadIdx.x;  // total NLAYER*96*DINNER
  int k = idx & (DINNER - 1);
  size_t rl = idx >> 11;  // / DINNER
  int row = (int)(rl % 96);
  int l = (int)(rl / 96);
  float v;
  if (row < 16)       v = WB[((size_t)l * DSTATE + row) * DINNER + k];
  else if (row < 32)  v = WC[((size_t)l * DSTATE + (row - 16)) * DINNER + k];
  else                v = Wdt1[((size_t)l * DTRANK + (row - 32)) * DINNER + k];
  out[idx] = v;
}

// ============================================================================
extern "C" void kernel_launch(void* const* d_in, const int* in_sizes, int n_in,
                              void* d_out, int out_size, void* d_ws, size_t ws_size,
                              hipStream_t stream) {
  (void)in_sizes; (void)n_in; (void)out_size;
  const int* token_ids = (const int*)d_in[0];
  const float* embed = (const float*)d_in[1];
  const float* Wres = (const float*)d_in[2];
  const float* Win = (const float*)d_in[3];
  const float* Wconv = (const float*)d_in[4];
  const float* WB = (const float*)d_in[5];
  const float* WC = (const float*)d_in[6];
  const float* Wdt1 = (const float*)d_in[7];
  const float* Wdt2 = (const float*)d_in[8];
  const float* bdt = (const float*)d_in[9];
  const float* logA = (const float*)d_in[10];
  const float* Dp = (const float*)d_in[11];
  const float* Wout = (const float*)d_in[12];
  float* out = (float*)d_out;

  char* w = (char*)d_ws;
  auto alloc = [&](size_t bytes) {
    char* p = w;
    w += (bytes + 255) & ~(size_t)255;
    return p;
  };
  ushort* eb    = (ushort*)alloc((size_t)VOCAB * DMODEL * 2);
  ushort* wresb = (ushort*)alloc((size_t)NLAYER * DINNER * DMODEL * 2);
  ushort* winb  = (ushort*)alloc((size_t)NLAYER * DINNER * DMODEL * 2);
  ushort* woutb = (ushort*)alloc((size_t)NLAYER * DMODEL * DINNER * 2);
  float* wbcdt  = (float*)alloc((size_t)NLAYER * 96 * DINNER * 4);
  float* x      = (float*)alloc((size_t)SEQ * DMODEL * 4);
  ushort* xnb   = (ushort*)alloc((size_t)SEQ * DMODEL * 2);
  float* res    = (float*)alloc((size_t)SEQ * DINNER * 4);
  float* u0     = (float*)alloc((size_t)SEQ * DINNER * 4);
  float* u      = (float*)alloc((size_t)SEQ * DINNER * 4);
  float* bcdt   = (float*)alloc((size_t)SEQ * 96 * 4);
  float* dt     = (float*)alloc((size_t)SEQ * DINNER * 4);
  float* y      = (float*)alloc((size_t)SEQ * DINNER * 4);
  ushort* y2b   = (ushort*)alloc((size_t)SEQ * DINNER * 2);
  ushort* xb    = (ushort*)alloc((size_t)SEQ * DMODEL * 2);
  if ((size_t)(w - (char*)d_ws) > ws_size) return;  // ws too small: fail visibly

  // weight preprocessing
  cast_bf16_kernel<<<VOCAB * DMODEL / 4 / 256, 256, 0, stream>>>(embed, eb, (size_t)VOCAB * DMODEL / 4);
  cast_bf16_kernel<<<NLAYER * DINNER * DMODEL / 4 / 256, 256, 0, stream>>>(Wres, wresb, (size_t)NLAYER * DINNER * DMODEL / 4);
  cast_bf16_kernel<<<NLAYER * DINNER * DMODEL / 4 / 256, 256, 0, stream>>>(Win, winb, (size_t)NLAYER * DINNER * DMODEL / 4);
  cast_bf16_kernel<<<NLAYER * DMODEL * DINNER / 4 / 256, 256, 0, stream>>>(Wout, woutb, (size_t)NLAYER * DMODEL * DINNER / 4);
  concat_wbcdt_kernel<<<NLAYER * 96 * DINNER / 256, 256, 0, stream>>>(WB, WC, Wdt1, wbcdt);
  gather_kernel<<<SEQ, 256, 0, stream>>>(token_ids, embed, x);

  for (int i = 0; i < NLAYER; ++i) {
    const ushort* wresi = wresb + (size_t)i * DINNER * DMODEL;
    const ushort* wini = winb + (size_t)i * DINNER * DMODEL;
    const ushort* wouti = woutb + (size_t)i * DMODEL * DINNER;
    const float* wconvi = Wconv + (size_t)i * DINNER * 4;
    const float* wbcdti = wbcdt + (size_t)i * 96 * DINNER;
    const float* wdt2i = Wdt2 + (size_t)i * DINNER * DTRANK;
    const float* bdti = bdt + (size_t)i * DINNER;
    const float* logAi = logA + (size_t)i * DINNER * DSTATE;
    const float* Dpi = Dp + (size_t)i * DINNER;

    rmsnorm_kernel<<<SEQ, 256, 0, stream>>>(x, xnb);
    dim3 g1(SEQ / 128, DINNER / 128);
    gemm_bt_bf16<<<g1, 256, 0, stream>>>(xnb, wresi, nullptr, res, SEQ, DINNER, DMODEL);
    gemm_bt_bf16<<<g1, 256, 0, stream>>>(xnb, wini, nullptr, u0, SEQ, DINNER, DMODEL);
    conv_silu_kernel<<<SEQ * DINNER / 4 / 256, 256, 0, stream>>>(u0, wconvi, u);
    smallgemm_f32<<<dim3(SEQ / 64, 2), 256, 0, stream>>>(
        u, DINNER, wbcdti, DINNER, bcdt, 96, nullptr, SEQ, 96, DINNER, 0);
    smallgemm_f32<<<dim3(SEQ / 64, DINNER / 64), 256, 0, stream>>>(
        bcdt + 32, 96, wdt2i, DTRANK, dt, DINNER, bdti, SEQ, DINNER, DTRANK, 1);
    scan_kernel<<<DINNER / 16, 256, 0, stream>>>(dt, u, bcdt, logAi, Dpi, y);
    ymul_cast_kernel<<<SEQ * DINNER / 4 / 256, 256, 0, stream>>>(y, res, y2b);
    dim3 g2(SEQ / 128, DMODEL / 128);
    gemm_bt_bf16<<<g2, 256, 0, stream>>>(y2b, wouti, x, x, SEQ, DMODEL, DINNER);
  }
  cast_bf16_kernel<<<SEQ * DMODEL / 4 / 256, 256, 0, stream>>>(x, xb, (size_t)SEQ * DMODEL / 4);
  dim3 g3(SEQ / 128, VOCAB / 128);
  gemm_bt_bf16<<<g3, 256, 0, stream>>>(xb, eb, nullptr, out, SEQ, VOCAB, DMODEL);
}

// Round 2
// 4472.829 us; speedup vs baseline: 1.7860x; 1.7860x over previous
//
#include <hip/hip_runtime.h>

#define SEQ 2048
#define DMODEL 1024
#define DINNER 2048
#define DSTATE 16
#define DTRANK 64
#define NLAYER 8
#define VOCAB 32000
#define NCHUNK 32
#define CLEN 64  // SEQ / NCHUNK

typedef float f32x4 __attribute__((ext_vector_type(4)));
typedef short bf16x8 __attribute__((ext_vector_type(8)));

__device__ __forceinline__ ushort f2bf(float f) {
  union { float f; unsigned u; } v; v.f = f;
  unsigned r = v.u + 0x7fffu + ((v.u >> 16) & 1u);
  return (ushort)(r >> 16);
}

__device__ __forceinline__ void lds_load16(const void* g, void* l) {
  __builtin_amdgcn_global_load_lds(
      (const __attribute__((address_space(1))) void*)g,
      (__attribute__((address_space(3))) void*)l, 16, 0, 0);
}

// ---------------- bf16 MFMA GEMM:  C[M,N] = A[M,K] @ B[N,K]^T (+ addsrc) ----
__global__ __launch_bounds__(256) void gemm_bt_bf16(
    const ushort* __restrict__ A, const ushort* __restrict__ B,
    const float* __restrict__ addsrc, float* __restrict__ C,
    int M, int N, int K)
{
  __shared__ __align__(16) ushort As[128 * 64];
  __shared__ __align__(16) ushort Bs[128 * 64];
  const int tid = threadIdx.x;
  const int lane = tid & 63;
  const int wave = tid >> 6;
  const int wr = wave >> 1, wc = wave & 1;
  const int bm = blockIdx.x * 128;
  const int bn = blockIdx.y * 128;
  const int rr = lane & 15, kq = lane >> 4;

  f32x4 acc[4][4];
#pragma unroll
  for (int m = 0; m < 4; ++m)
#pragma unroll
    for (int n = 0; n < 4; ++n) acc[m][n] = (f32x4){0.f, 0.f, 0.f, 0.f};

  for (int kt = 0; kt < K; kt += 64) {
#pragma unroll
    for (int i = 0; i < 4; ++i) {
      int fb = i * 256 + tid;
      int row = fb >> 3, cb = fb & 7;
      lds_load16(A + (size_t)(bm + row) * K + kt + cb * 8, (void*)(As + (size_t)fb * 8));
      lds_load16(B + (size_t)(bn + row) * K + kt + cb * 8, (void*)(Bs + (size_t)fb * 8));
    }
    __syncthreads();
#pragma unroll
    for (int ks = 0; ks < 2; ++ks) {
      bf16x8 af[4], bfr[4];
      const int koff = ks * 32 + kq * 8;
#pragma unroll
      for (int m = 0; m < 4; ++m)
        af[m] = *(const bf16x8*)&As[(wr * 64 + m * 16 + rr) * 64 + koff];
#pragma unroll
      for (int n = 0; n < 4; ++n)
        bfr[n] = *(const bf16x8*)&Bs[(wc * 64 + n * 16 + rr) * 64 + koff];
#pragma unroll
      for (int m = 0; m < 4; ++m)
#pragma unroll
        for (int n = 0; n < 4; ++n)
          acc[m][n] = __builtin_amdgcn_mfma_f32_16x16x32_bf16(af[m], bfr[n], acc[m][n], 0, 0, 0);
    }
    __syncthreads();
  }
#pragma unroll
  for (int m = 0; m < 4; ++m) {
    const int r0 = bm + wr * 64 + m * 16 + kq * 4;
#pragma unroll
    for (int n = 0; n < 4; ++n) {
      const int cc = bn + wc * 64 + n * 16 + rr;
#pragma unroll
      for (int j = 0; j < 4; ++j) {
        size_t idx = (size_t)(r0 + j) * N + cc;
        float v = acc[m][n][j];
        if (addsrc) v += addsrc[idx];
        C[idx] = v;
      }
    }
  }
}

// ---------------- f32 small GEMM: C[M,N] = A[M,K(lda)] @ W[N,K(ldw)]^T ------
__global__ __launch_bounds__(256) void smallgemm_f32(
    const float* __restrict__ A, int lda,
    const float* __restrict__ W, int ldw,
    float* __restrict__ C, int ldc,
    const float* __restrict__ bias,
    int M, int N, int K, int act)
{
  __shared__ float As[64][65];
  __shared__ float Ws[64][65];
  const int t = threadIdx.x;
  const int bm = blockIdx.x * 64, bn = blockIdx.y * 64;
  const int r0 = (t >> 4) * 4;
  const int c0 = (t & 15) * 4;
  float acc[4][4] = {};

  for (int kt = 0; kt < K; kt += 64) {
#pragma unroll
    for (int i = 0; i < 16; ++i) {
      int idx = i * 256 + t;
      int r = idx >> 6, c = idx & 63;
      As[r][c] = A[(size_t)(bm + r) * lda + kt + c];
      int wrow = bn + r;
      Ws[r][c] = (wrow < N) ? W[(size_t)wrow * ldw + kt + c] : 0.f;
    }
    __syncthreads();
#pragma unroll 8
    for (int kk = 0; kk < 64; ++kk) {
      float a0 = As[r0][kk], a1 = As[r0 + 1][kk], a2 = As[r0 + 2][kk], a3 = As[r0 + 3][kk];
      float w0 = Ws[c0][kk], w1 = Ws[c0 + 1][kk], w2 = Ws[c0 + 2][kk], w3 = Ws[c0 + 3][kk];
      acc[0][0] += a0 * w0; acc[0][1] += a0 * w1; acc[0][2] += a0 * w2; acc[0][3] += a0 * w3;
      acc[1][0] += a1 * w0; acc[1][1] += a1 * w1; acc[1][2] += a1 * w2; acc[1][3] += a1 * w3;
      acc[2][0] += a2 * w0; acc[2][1] += a2 * w1; acc[2][2] += a2 * w2; acc[2][3] += a2 * w3;
      acc[3][0] += a3 * w0; acc[3][1] += a3 * w1; acc[3][2] += a3 * w2; acc[3][3] += a3 * w3;
    }
    __syncthreads();
  }
#pragma unroll
  for (int i = 0; i < 4; ++i)
#pragma unroll
    for (int j = 0; j < 4; ++j) {
      int cc = bn + c0 + j;
      if (cc < N) {
        float v = acc[i][j];
        if (bias) v += bias[cc];
        if (act == 1) v = (v > 20.f) ? v : log1pf(expf(v));
        C[(size_t)(bm + r0 + i) * ldc + cc] = v;
      }
    }
}

// ---------------- embedding gather ------------------------------------------
__global__ __launch_bounds__(256) void gather_kernel(
    const int* __restrict__ ids, const float* __restrict__ embed, float* __restrict__ x)
{
  int row = blockIdx.x;
  int id = ids[row];
  ((float4*)x)[(size_t)row * (DMODEL / 4) + threadIdx.x] =
      ((const float4*)(embed + (size_t)id * DMODEL))[threadIdx.x];
}

// ---------------- RMSNorm (no scale) -> bf16 --------------------------------
__global__ __launch_bounds__(256) void rmsnorm_kernel(
    const float* __restrict__ x, ushort* __restrict__ xnb)
{
  int row = blockIdx.x;
  float4 v = ((const float4*)(x + (size_t)row * DMODEL))[threadIdx.x];
  float s = v.x * v.x + v.y * v.y + v.z * v.z + v.w * v.w;
#pragma unroll
  for (int o = 32; o > 0; o >>= 1) s += __shfl_down(s, o);
  __shared__ float ws[4];
  if ((threadIdx.x & 63) == 0) ws[threadIdx.x >> 6] = s;
  __syncthreads();
  float tot = ws[0] + ws[1] + ws[2] + ws[3];
  float sc = rsqrtf(tot * (1.0f / DMODEL) + 1e-6f);
  ushort4 o4 = {f2bf(v.x * sc), f2bf(v.y * sc), f2bf(v.z * sc), f2bf(v.w * sc)};
  ((ushort4*)xnb)[(size_t)row * (DMODEL / 4) + threadIdx.x] = o4;
}

// ---------------- causal depthwise conv (K=4) + SiLU ------------------------
__global__ __launch_bounds__(256) void conv_silu_kernel(
    const float* __restrict__ u0, int ld, const float* __restrict__ Wconv,
    float* __restrict__ u)
{
  int idx = blockIdx.x * 256 + threadIdx.x;  // over SEQ * DINNER/4
  int d4 = idx & (DINNER / 4 - 1);
  int l = idx >> 9;
  int d0 = d4 * 4;
  float wt[4][4];
#pragma unroll
  for (int j = 0; j < 4; ++j) {
    float4 tv = *(const float4*)&Wconv[(d0 + j) * 4];
    wt[j][0] = tv.x; wt[j][1] = tv.y; wt[j][2] = tv.z; wt[j][3] = tv.w;
  }
  float a[4] = {0.f, 0.f, 0.f, 0.f};
#pragma unroll
  for (int k = 0; k < 4; ++k) {
    int ls = l - 3 + k;
    if (ls >= 0) {
      float4 uv = *(const float4*)&u0[(size_t)ls * ld + d0];
      a[0] += uv.x * wt[0][k];
      a[1] += uv.y * wt[1][k];
      a[2] += uv.z * wt[2][k];
      a[3] += uv.w * wt[3][k];
    }
  }
  float4 r;
  r.x = a[0] / (1.f + expf(-a[0]));
  r.y = a[1] / (1.f + expf(-a[1]));
  r.z = a[2] / (1.f + expf(-a[2]));
  r.w = a[3] / (1.f + expf(-a[3]));
  *(float4*)&u[(size_t)l * DINNER + d0] = r;
}

// ---------------- chunk-parallel selective scan -----------------------------
// pass1: local scan per chunk (h0=0) -> P = prod(dA), S = final local h
__global__ __launch_bounds__(256) void scan_pass1(
    const float* __restrict__ dt, const float* __restrict__ u,
    const float* __restrict__ bcdt, const float* __restrict__ logA,
    float* __restrict__ P, float* __restrict__ S)
{
  const int tid = threadIdx.x;
  const int n = tid & 15, dl = tid >> 4;
  const int dbase = blockIdx.x * 16;
  const int c = blockIdx.y;
  const int t0 = c * CLEN;
  const int d = dbase + dl;
  const float Aval = -expf(logA[d * DSTATE + n]);
  __shared__ float sdt[CLEN][16], su[CLEN][16], sB[CLEN][16];
  {
    int tt = tid >> 2, j0 = (tid & 3) * 4;
    *(float4*)&sdt[tt][j0] = *(const float4*)&dt[(size_t)(t0 + tt) * DINNER + dbase + j0];
    *(float4*)&su[tt][j0]  = *(const float4*)&u[(size_t)(t0 + tt) * DINNER + dbase + j0];
    *(float4*)&sB[tt][j0]  = *(const float4*)&bcdt[(size_t)(t0 + tt) * 96 + j0];
  }
  __syncthreads();
  float h = 0.f, pr = 1.f;
#pragma unroll 8
  for (int i = 0; i < CLEN; ++i) {
    float dtv = sdt[i][dl], uv = su[i][dl], Bv = sB[i][n];
    float dtA = dtv * Aval;
    float rinv = __builtin_amdgcn_rcpf(1.f - 0.5f * dtA);
    float dA = (1.f + 0.5f * dtA) * rinv;
    float dBu = dtv * Bv * rinv * uv;
    h = dA * h + dBu;
    pr *= dA;
  }
  size_t idx = (size_t)c * (DINNER * DSTATE) + (size_t)d * DSTATE + n;
  P[idx] = pr;
  S[idx] = h;
}

// combine: sequential over chunks (32 steps) -> exact chunk-entry states
__global__ __launch_bounds__(256) void scan_combine(
    const float* __restrict__ P, const float* __restrict__ S, float* __restrict__ Hinit)
{
  int idx = blockIdx.x * 256 + threadIdx.x;  // over DINNER*DSTATE
  float H = 0.f;
#pragma unroll
  for (int c = 0; c < NCHUNK; ++c) {
    size_t o = (size_t)c * (DINNER * DSTATE) + idx;
    Hinit[o] = H;
    H = P[o] * H + S[o];
  }
}

// pass2: re-scan chunk from Hinit; reduce over states; fuse y*silu(res)->bf16
__global__ __launch_bounds__(256) void scan_pass2(
    const float* __restrict__ dt, const float* __restrict__ u,
    const float* __restrict__ bcdt, const float* __restrict__ logA,
    const float* __restrict__ Dp, const float* __restrict__ Hinit,
    const float* __restrict__ resu0, ushort* __restrict__ y2b)
{
  const int tid = threadIdx.x;
  const int n = tid & 15, dl = tid >> 4;
  const int dbase = blockIdx.x * 16;
  const int c = blockIdx.y;
  const int t0 = c * CLEN;
  const int d = dbase + dl;
  const float Aval = -expf(logA[d * DSTATE + n]);
  const float Dpv = Dp[d];
  __shared__ float sdt[CLEN][16], su[CLEN][16], sB[CLEN][16], sC[CLEN][16], sres[CLEN][16];
  {
    int tt = tid >> 2, j0 = (tid & 3) * 4;
    *(float4*)&sdt[tt][j0]  = *(const float4*)&dt[(size_t)(t0 + tt) * DINNER + dbase + j0];
    *(float4*)&su[tt][j0]   = *(const float4*)&u[(size_t)(t0 + tt) * DINNER + dbase + j0];
    *(float4*)&sB[tt][j0]   = *(const float4*)&bcdt[(size_t)(t0 + tt) * 96 + j0];
    *(float4*)&sC[tt][j0]   = *(const float4*)&bcdt[(size_t)(t0 + tt) * 96 + 16 + j0];
    *(float4*)&sres[tt][j0] = *(const float4*)&resu0[(size_t)(t0 + tt) * (2 * DINNER) + dbase + j0];
  }
  __syncthreads();
  float h = Hinit[(size_t)c * (DINNER * DSTATE) + (size_t)d * DSTATE + n];
#pragma unroll 4
  for (int i = 0; i < CLEN; ++i) {
    float dtv = sdt[i][dl], uv = su[i][dl];
    float dtA = dtv * Aval;
    float rinv = __builtin_amdgcn_rcpf(1.f - 0.5f * dtA);
    float dA = (1.f + 0.5f * dtA) * rinv;
    float dBu = dtv * sB[i][n] * rinv * uv;
    h = dA * h + dBu;
    float p = h * sC[i][n];
    p += __shfl_xor(p, 1);
    p += __shfl_xor(p, 2);
    p += __shfl_xor(p, 4);
    p += __shfl_xor(p, 8);
    if (n == 0) {
      float rv = sres[i][dl];
      float yv = (p + uv * Dpv) * (rv / (1.f + expf(-rv)));
      y2b[(size_t)(t0 + i) * DINNER + d] = f2bf(yv);
    }
  }
}

// ---------------- f32 -> bf16 cast ------------------------------------------
__global__ __launch_bounds__(256) void cast_bf16_kernel(
    const float* __restrict__ in, ushort* __restrict__ out, size_t n4)
{
  size_t i = (size_t)blockIdx.x * 256 + threadIdx.x;
  if (i >= n4) return;
  float4 v = ((const float4*)in)[i];
  ushort4 o = {f2bf(v.x), f2bf(v.y), f2bf(v.z), f2bf(v.w)};
  ((ushort4*)out)[i] = o;
}

// ---------------- concat-cast Wres|Win -> bf16 [L][2*DINNER][DMODEL] --------
__global__ __launch_bounds__(256) void cast_cat2_kernel(
    const float* __restrict__ Wres, const float* __restrict__ Win, ushort* __restrict__ out)
{
  size_t i4 = (size_t)blockIdx.x * 256 + threadIdx.x;  // over L*4096*1024/4
  size_t e0 = i4 * 4;
  int k = (int)(e0 & (DMODEL - 1));
  int r = (int)((e0 >> 10) & (2 * DINNER - 1));
  int l = (int)(e0 >> 22);
  const float* src = (r < DINNER)
      ? &Wres[(((size_t)l * DINNER + r) << 10) + k]
      : &Win[(((size_t)l * DINNER + (r - DINNER)) << 10) + k];
  float4 v = *(const float4*)src;
  ushort4 o = {f2bf(v.x), f2bf(v.y), f2bf(v.z), f2bf(v.w)};
  ((ushort4*)out)[i4] = o;
}

// ---------------- concat WB|WC|Wdt1 -> [L][96][DINNER] ----------------------
__global__ __launch_bounds__(256) void concat_wbcdt_kernel(
    const float* __restrict__ WB, const float* __restrict__ WC,
    const float* __restrict__ Wdt1, float* __restrict__ out)
{
  size_t idx = (size_t)blockIdx.x * 256 + threadIdx.x;
  int k = idx & (DINNER - 1);
  size_t rl = idx >> 11;
  int row = (int)(rl % 96);
  int l = (int)(rl / 96);
  float v;
  if (row < 16)       v = WB[((size_t)l * DSTATE + row) * DINNER + k];
  else if (row < 32)  v = WC[((size_t)l * DSTATE + (row - 16)) * DINNER + k];
  else                v = Wdt1[((size_t)l * DTRANK + (row - 32)) * DINNER + k];
  out[idx] = v;
}

// ============================================================================
extern "C" void kernel_launch(void* const* d_in, const int* in_sizes, int n_in,
                              void* d_out, int out_size, void* d_ws, size_t ws_size,
                              hipStream_t stream) {
  (void)in_sizes; (void)n_in; (void)out_size;
  const int* token_ids = (const int*)d_in[0];
  const float* embed = (const float*)d_in[1];
  const float* Wres = (const float*)d_in[2];
  const float* Win = (const float*)d_in[3];
  const float* Wconv = (const float*)d_in[4];
  const float* WB = (const float*)d_in[5];
  const float* WC = (const float*)d_in[6];
  const float* Wdt1 = (const float*)d_in[7];
  const float* Wdt2 = (const float*)d_in[8];
  const float* bdt = (const float*)d_in[9];
  const float* logA = (const float*)d_in[10];
  const float* Dp = (const float*)d_in[11];
  const float* Wout = (const float*)d_in[12];
  float* out = (float*)d_out;

  char* w = (char*)d_ws;
  auto alloc = [&](size_t bytes) {
    char* p = w;
    w += (bytes + 255) & ~(size_t)255;
    return p;
  };
  ushort* eb    = (ushort*)alloc((size_t)VOCAB * DMODEL * 2);
  ushort* wcatb = (ushort*)alloc((size_t)NLAYER * 2 * DINNER * DMODEL * 2);
  ushort* woutb = (ushort*)alloc((size_t)NLAYER * DMODEL * DINNER * 2);
  float* wbcdt  = (float*)alloc((size_t)NLAYER * 96 * DINNER * 4);
  float* x      = (float*)alloc((size_t)SEQ * DMODEL * 4);
  ushort* xnb   = (ushort*)alloc((size_t)SEQ * DMODEL * 2);
  float* resu0  = (float*)alloc((size_t)SEQ * 2 * DINNER * 4);
  float* u      = (float*)alloc((size_t)SEQ * DINNER * 4);
  float* bcdt   = (float*)alloc((size_t)SEQ * 96 * 4);
  float* dt     = (float*)alloc((size_t)SEQ * DINNER * 4);
  float* Pbuf   = (float*)alloc((size_t)NCHUNK * DINNER * DSTATE * 4);
  float* Sbuf   = (float*)alloc((size_t)NCHUNK * DINNER * DSTATE * 4);
  float* Hinit  = (float*)alloc((size_t)NCHUNK * DINNER * DSTATE * 4);
  ushort* y2b   = (ushort*)alloc((size_t)SEQ * DINNER * 2);
  ushort* xb    = (ushort*)alloc((size_t)SEQ * DMODEL * 2);
  if ((size_t)(w - (char*)d_ws) > ws_size) return;

  // weight preprocessing
  cast_bf16_kernel<<<VOCAB * DMODEL / 4 / 256, 256, 0, stream>>>(embed, eb, (size_t)VOCAB * DMODEL / 4);
  cast_cat2_kernel<<<NLAYER * 2 * DINNER * DMODEL / 4 / 256, 256, 0, stream>>>(Wres, Win, wcatb);
  cast_bf16_kernel<<<NLAYER * DMODEL * DINNER / 4 / 256, 256, 0, stream>>>(Wout, woutb, (size_t)NLAYER * DMODEL * DINNER / 4);
  concat_wbcdt_kernel<<<NLAYER * 96 * DINNER / 256, 256, 0, stream>>>(WB, WC, Wdt1, wbcdt);
  gather_kernel<<<SEQ, 256, 0, stream>>>(token_ids, embed, x);

  for (int i = 0; i < NLAYER; ++i) {
    const ushort* wcati = wcatb + (size_t)i * 2 * DINNER * DMODEL;
    const ushort* wouti = woutb + (size_t)i * DMODEL * DINNER;
    const float* wconvi = Wconv + (size_t)i * DINNER * 4;
    const float* wbcdti = wbcdt + (size_t)i * 96 * DINNER;
    const float* wdt2i = Wdt2 + (size_t)i * DINNER * DTRANK;
    const float* bdti = bdt + (size_t)i * DINNER;
    const float* logAi = logA + (size_t)i * DINNER * DSTATE;
    const float* Dpi = Dp + (size_t)i * DINNER;

    rmsnorm_kernel<<<SEQ, 256, 0, stream>>>(x, xnb);
    dim3 g1(SEQ / 128, 2 * DINNER / 128);
    gemm_bt_bf16<<<g1, 256, 0, stream>>>(xnb, wcati, nullptr, resu0, SEQ, 2 * DINNER, DMODEL);
    conv_silu_kernel<<<SEQ * DINNER / 4 / 256, 256, 0, stream>>>(resu0 + DINNER, 2 * DINNER, wconvi, u);
    smallgemm_f32<<<dim3(SEQ / 64, 2), 256, 0, stream>>>(
        u, DINNER, wbcdti, DINNER, bcdt, 96, nullptr, SEQ, 96, DINNER, 0);
    smallgemm_f32<<<dim3(SEQ / 64, DINNER / 64), 256, 0, stream>>>(
        bcdt + 32, 96, wdt2i, DTRANK, dt, DINNER, bdti, SEQ, DINNER, DTRANK, 1);
    dim3 gs(DINNER / 16, NCHUNK);
    scan_pass1<<<gs, 256, 0, stream>>>(dt, u, bcdt, logAi, Pbuf, Sbuf);
    scan_combine<<<DINNER * DSTATE / 256, 256, 0, stream>>>(Pbuf, Sbuf, Hinit);
    scan_pass2<<<gs, 256, 0, stream>>>(dt, u, bcdt, logAi, Dpi, Hinit, resu0, y2b);
    dim3 g2(SEQ / 128, DMODEL / 128);
    gemm_bt_bf16<<<g2, 256, 0, stream>>>(y2b, wouti, x, x, SEQ, DMODEL, DINNER);
  }
  cast_bf16_kernel<<<SEQ * DMODEL / 4 / 256, 256, 0, stream>>>(x, xb, (size_t)SEQ * DMODEL / 4);
  dim3 g3(SEQ / 128, VOCAB / 128);
  gemm_bt_bf16<<<g3, 256, 0, stream>>>(xb, eb, nullptr, out, SEQ, VOCAB, DMODEL);
}

// Round 3
// 2625.410 us; speedup vs baseline: 3.0428x; 1.7037x over previous
//
#include <hip/hip_runtime.h>

#define SEQ 2048
#define DMODEL 1024
#define DINNER 2048
#define DSTATE 16
#define DTRANK 64
#define NLAYER 8
#define VOCAB 32000
#define NCHUNK 32
#define CLEN 64   // SEQ / NCHUNK
#define PROJ_NCH 16
#define PROJ_KC 128  // DINNER / PROJ_NCH

typedef float f32x4 __attribute__((ext_vector_type(4)));
typedef short bf16x8 __attribute__((ext_vector_type(8)));

__device__ __forceinline__ ushort f2bf(float f) {
  union { float f; unsigned u; } v; v.f = f;
  unsigned r = v.u + 0x7fffu + ((v.u >> 16) & 1u);
  return (ushort)(r >> 16);
}

__device__ __forceinline__ void lds_load16(const void* g, void* l) {
  __builtin_amdgcn_global_load_lds(
      (const __attribute__((address_space(1))) void*)g,
      (__attribute__((address_space(3))) void*)l, 16, 0, 0);
}

// ---------------- bf16 MFMA GEMM:  C[M,N] = A[M,K] @ B[N,K]^T (+ addsrc) ----
// 128x128 tile, BK=64, 4 waves, 16x16x32 MFMA, XCD-swizzled block mapping.
__global__ __launch_bounds__(256) void gemm_bt_bf16(
    const ushort* __restrict__ A, const ushort* __restrict__ B,
    const float* __restrict__ addsrc, float* __restrict__ C,
    int M, int N, int K)
{
  __shared__ __align__(16) ushort As[128 * 64];
  __shared__ __align__(16) ushort Bs[128 * 64];
  const int tid = threadIdx.x;
  const int lane = tid & 63;
  const int wave = tid >> 6;
  const int wr = wave >> 1, wc = wave & 1;

  // bijective XCD swizzle: each XCD gets a contiguous chunk of linear ids
  unsigned nwg = gridDim.x * gridDim.y;
  unsigned lb = blockIdx.y * gridDim.x + blockIdx.x;
  if ((nwg & 7u) == 0u) {
    unsigned cpx = nwg >> 3;
    lb = (lb & 7u) * cpx + (lb >> 3);
  }
  const int bm = (lb % gridDim.x) * 128;
  const int bn = (lb / gridDim.x) * 128;
  const int rr = lane & 15, kq = lane >> 4;

  f32x4 acc[4][4];
#pragma unroll
  for (int m = 0; m < 4; ++m)
#pragma unroll
    for (int n = 0; n < 4; ++n) acc[m][n] = (f32x4){0.f, 0.f, 0.f, 0.f};

  for (int kt = 0; kt < K; kt += 64) {
#pragma unroll
    for (int i = 0; i < 4; ++i) {
      int fb = i * 256 + tid;
      int row = fb >> 3, cb = fb & 7;
      lds_load16(A + (size_t)(bm + row) * K + kt + cb * 8, (void*)(As + (size_t)fb * 8));
      lds_load16(B + (size_t)(bn + row) * K + kt + cb * 8, (void*)(Bs + (size_t)fb * 8));
    }
    __syncthreads();
#pragma unroll
    for (int ks = 0; ks < 2; ++ks) {
      bf16x8 af[4], bfr[4];
      const int koff = ks * 32 + kq * 8;
#pragma unroll
      for (int m = 0; m < 4; ++m)
        af[m] = *(const bf16x8*)&As[(wr * 64 + m * 16 + rr) * 64 + koff];
#pragma unroll
      for (int n = 0; n < 4; ++n)
        bfr[n] = *(const bf16x8*)&Bs[(wc * 64 + n * 16 + rr) * 64 + koff];
#pragma unroll
      for (int m = 0; m < 4; ++m)
#pragma unroll
        for (int n = 0; n < 4; ++n)
          acc[m][n] = __builtin_amdgcn_mfma_f32_16x16x32_bf16(af[m], bfr[n], acc[m][n], 0, 0, 0);
    }
    __syncthreads();
  }
#pragma unroll
  for (int m = 0; m < 4; ++m) {
    const int r0 = bm + wr * 64 + m * 16 + kq * 4;
#pragma unroll
    for (int n = 0; n < 4; ++n) {
      const int cc = bn + wc * 64 + n * 16 + rr;
#pragma unroll
      for (int j = 0; j < 4; ++j) {
        size_t idx = (size_t)(r0 + j) * N + cc;
        float v = acc[m][n][j];
        if (addsrc) v += addsrc[idx];
        C[idx] = v;
      }
    }
  }
}

// ---------------- split-K f32 projection GEMM: Cp[ch] = A@W^T chunk ---------
// A[M,2048], W[96,2048]; grid (M/64, PROJ_NCH); per-thread 4x6 register tile.
__global__ __launch_bounds__(256) void projgemm_f32(
    const float* __restrict__ A, const float* __restrict__ W,
    float* __restrict__ Cp, int M)
{
  __shared__ float As[64][65];
  __shared__ float Ws[96][65];
  const int t = threadIdx.x;
  const int bm = blockIdx.x * 64;
  const int kc = blockIdx.y * PROJ_KC;
  const int ty = t >> 4, tx = t & 15;
  const int r0 = ty * 4, c0 = tx * 6;
  float acc[4][6] = {};
  for (int kt = 0; kt < PROJ_KC; kt += 64) {
#pragma unroll
    for (int i = 0; i < 4; ++i) {
      int e4 = i * 256 + t;
      int r = e4 >> 4, c4 = (e4 & 15) * 4;
      *(float4*)&As[r][c4] = *(const float4*)&A[(size_t)(bm + r) * DINNER + kc + kt + c4];
    }
#pragma unroll
    for (int i = 0; i < 6; ++i) {
      int e4 = i * 256 + t;
      int r = e4 >> 4, c4 = (e4 & 15) * 4;
      *(float4*)&Ws[r][c4] = *(const float4*)&W[(size_t)r * DINNER + kc + kt + c4];
    }
    __syncthreads();
#pragma unroll 4
    for (int kk = 0; kk < 64; ++kk) {
      float a0 = As[r0][kk], a1 = As[r0 + 1][kk], a2 = As[r0 + 2][kk], a3 = As[r0 + 3][kk];
      float w0 = Ws[c0][kk], w1 = Ws[c0 + 1][kk], w2 = Ws[c0 + 2][kk];
      float w3 = Ws[c0 + 3][kk], w4 = Ws[c0 + 4][kk], w5 = Ws[c0 + 5][kk];
      acc[0][0] += a0 * w0; acc[0][1] += a0 * w1; acc[0][2] += a0 * w2;
      acc[0][3] += a0 * w3; acc[0][4] += a0 * w4; acc[0][5] += a0 * w5;
      acc[1][0] += a1 * w0; acc[1][1] += a1 * w1; acc[1][2] += a1 * w2;
      acc[1][3] += a1 * w3; acc[1][4] += a1 * w4; acc[1][5] += a1 * w5;
      acc[2][0] += a2 * w0; acc[2][1] += a2 * w1; acc[2][2] += a2 * w2;
      acc[2][3] += a2 * w3; acc[2][4] += a2 * w4; acc[2][5] += a2 * w5;
      acc[3][0] += a3 * w0; acc[3][1] += a3 * w1; acc[3][2] += a3 * w2;
      acc[3][3] += a3 * w3; acc[3][4] += a3 * w4; acc[3][5] += a3 * w5;
    }
    __syncthreads();
  }
  float* cp = Cp + (size_t)blockIdx.y * M * 96;
#pragma unroll
  for (int i = 0; i < 4; ++i)
#pragma unroll
    for (int j = 0; j < 6; ++j)
      cp[(size_t)(bm + r0 + i) * 96 + c0 + j] = acc[i][j];
}

__global__ __launch_bounds__(256) void proj_reduce(
    const float* __restrict__ Cp, float* __restrict__ bcdt, int M)
{
  int idx = blockIdx.x * 256 + threadIdx.x;  // over M*96
  float s = 0.f;
#pragma unroll
  for (int c = 0; c < PROJ_NCH; ++c) s += Cp[(size_t)c * M * 96 + idx];
  bcdt[idx] = s;
}

// ---------------- f32 small GEMM: C[M,N] = A[M,K(lda)] @ W[N,K(ldw)]^T ------
__global__ __launch_bounds__(256) void smallgemm_f32(
    const float* __restrict__ A, int lda,
    const float* __restrict__ W, int ldw,
    float* __restrict__ C, int ldc,
    const float* __restrict__ bias,
    int M, int N, int K, int act)
{
  __shared__ float As[64][65];
  __shared__ float Ws[64][65];
  const int t = threadIdx.x;
  const int bm = blockIdx.x * 64, bn = blockIdx.y * 64;
  const int r0 = (t >> 4) * 4;
  const int c0 = (t & 15) * 4;
  float acc[4][4] = {};

  for (int kt = 0; kt < K; kt += 64) {
#pragma unroll
    for (int i = 0; i < 16; ++i) {
      int idx = i * 256 + t;
      int r = idx >> 6, c = idx & 63;
      As[r][c] = A[(size_t)(bm + r) * lda + kt + c];
      int wrow = bn + r;
      Ws[r][c] = (wrow < N) ? W[(size_t)wrow * ldw + kt + c] : 0.f;
    }
    __syncthreads();
#pragma unroll 8
    for (int kk = 0; kk < 64; ++kk) {
      float a0 = As[r0][kk], a1 = As[r0 + 1][kk], a2 = As[r0 + 2][kk], a3 = As[r0 + 3][kk];
      float w0 = Ws[c0][kk], w1 = Ws[c0 + 1][kk], w2 = Ws[c0 + 2][kk], w3 = Ws[c0 + 3][kk];
      acc[0][0] += a0 * w0; acc[0][1] += a0 * w1; acc[0][2] += a0 * w2; acc[0][3] += a0 * w3;
      acc[1][0] += a1 * w0; acc[1][1] += a1 * w1; acc[1][2] += a1 * w2; acc[1][3] += a1 * w3;
      acc[2][0] += a2 * w0; acc[2][1] += a2 * w1; acc[2][2] += a2 * w2; acc[2][3] += a2 * w3;
      acc[3][0] += a3 * w0; acc[3][1] += a3 * w1; acc[3][2] += a3 * w2; acc[3][3] += a3 * w3;
    }
    __syncthreads();
  }
#pragma unroll
  for (int i = 0; i < 4; ++i)
#pragma unroll
    for (int j = 0; j < 4; ++j) {
      int cc = bn + c0 + j;
      if (cc < N) {
        float v = acc[i][j];
        if (bias) v += bias[cc];
        if (act == 1) v = (v > 20.f) ? v : log1pf(expf(v));
        C[(size_t)(bm + r0 + i) * ldc + cc] = v;
      }
    }
}

// ---------------- embedding gather ------------------------------------------
__global__ __launch_bounds__(256) void gather_kernel(
    const int* __restrict__ ids, const float* __restrict__ embed, float* __restrict__ x)
{
  int row = blockIdx.x;
  int id = ids[row];
  ((float4*)x)[(size_t)row * (DMODEL / 4) + threadIdx.x] =
      ((const float4*)(embed + (size_t)id * DMODEL))[threadIdx.x];
}

// ---------------- RMSNorm (no scale) -> bf16 --------------------------------
__global__ __launch_bounds__(256) void rmsnorm_kernel(
    const float* __restrict__ x, ushort* __restrict__ xnb)
{
  int row = blockIdx.x;
  float4 v = ((const float4*)(x + (size_t)row * DMODEL))[threadIdx.x];
  float s = v.x * v.x + v.y * v.y + v.z * v.z + v.w * v.w;
#pragma unroll
  for (int o = 32; o > 0; o >>= 1) s += __shfl_down(s, o);
  __shared__ float ws[4];
  if ((threadIdx.x & 63) == 0) ws[threadIdx.x >> 6] = s;
  __syncthreads();
  float tot = ws[0] + ws[1] + ws[2] + ws[3];
  float sc = rsqrtf(tot * (1.0f / DMODEL) + 1e-6f);
  ushort4 o4 = {f2bf(v.x * sc), f2bf(v.y * sc), f2bf(v.z * sc), f2bf(v.w * sc)};
  ((ushort4*)xnb)[(size_t)row * (DMODEL / 4) + threadIdx.x] = o4;
}

// ---------------- causal depthwise conv (K=4) + SiLU ------------------------
__global__ __launch_bounds__(256) void conv_silu_kernel(
    const float* __restrict__ u0, int ld, const float* __restrict__ Wconv,
    float* __restrict__ u)
{
  int idx = blockIdx.x * 256 + threadIdx.x;
  int d4 = idx & (DINNER / 4 - 1);
  int l = idx >> 9;
  int d0 = d4 * 4;
  float wt[4][4];
#pragma unroll
  for (int j = 0; j < 4; ++j) {
    float4 tv = *(const float4*)&Wconv[(d0 + j) * 4];
    wt[j][0] = tv.x; wt[j][1] = tv.y; wt[j][2] = tv.z; wt[j][3] = tv.w;
  }
  float a[4] = {0.f, 0.f, 0.f, 0.f};
#pragma unroll
  for (int k = 0; k < 4; ++k) {
    int ls = l - 3 + k;
    if (ls >= 0) {
      float4 uv = *(const float4*)&u0[(size_t)ls * ld + d0];
      a[0] += uv.x * wt[0][k];
      a[1] += uv.y * wt[1][k];
      a[2] += uv.z * wt[2][k];
      a[3] += uv.w * wt[3][k];
    }
  }
  float4 r;
  r.x = a[0] / (1.f + expf(-a[0]));
  r.y = a[1] / (1.f + expf(-a[1]));
  r.z = a[2] / (1.f + expf(-a[2]));
  r.w = a[3] / (1.f + expf(-a[3]));
  *(float4*)&u[(size_t)l * DINNER + d0] = r;
}

// ---------------- chunk-parallel selective scan -----------------------------
__global__ __launch_bounds__(256) void scan_pass1(
    const float* __restrict__ dt, const float* __restrict__ u,
    const float* __restrict__ bcdt, const float* __restrict__ logA,
    float* __restrict__ P, float* __restrict__ S)
{
  const int tid = threadIdx.x;
  const int n = tid & 15, dl = tid >> 4;
  const int dbase = blockIdx.x * 16;
  const int c = blockIdx.y;
  const int t0 = c * CLEN;
  const int d = dbase + dl;
  const float Aval = -expf(logA[d * DSTATE + n]);
  __shared__ float sdt[CLEN][16], su[CLEN][16], sB[CLEN][16];
  {
    int tt = tid >> 2, j0 = (tid & 3) * 4;
    *(float4*)&sdt[tt][j0] = *(const float4*)&dt[(size_t)(t0 + tt) * DINNER + dbase + j0];
    *(float4*)&su[tt][j0]  = *(const float4*)&u[(size_t)(t0 + tt) * DINNER + dbase + j0];
    *(float4*)&sB[tt][j0]  = *(const float4*)&bcdt[(size_t)(t0 + tt) * 96 + j0];
  }
  __syncthreads();
  float h = 0.f, pr = 1.f;
#pragma unroll 8
  for (int i = 0; i < CLEN; ++i) {
    float dtv = sdt[i][dl], uv = su[i][dl], Bv = sB[i][n];
    float dtA = dtv * Aval;
    float rinv = __builtin_amdgcn_rcpf(1.f - 0.5f * dtA);
    float dA = (1.f + 0.5f * dtA) * rinv;
    float dBu = dtv * Bv * rinv * uv;
    h = dA * h + dBu;
    pr *= dA;
  }
  size_t idx = (size_t)c * (DINNER * DSTATE) + (size_t)d * DSTATE + n;
  P[idx] = pr;
  S[idx] = h;
}

__global__ __launch_bounds__(256) void scan_combine(
    const float* __restrict__ P, const float* __restrict__ S, float* __restrict__ Hinit)
{
  int idx = blockIdx.x * 256 + threadIdx.x;
  float H = 0.f;
#pragma unroll
  for (int c = 0; c < NCHUNK; ++c) {
    size_t o = (size_t)c * (DINNER * DSTATE) + idx;
    Hinit[o] = H;
    H = P[o] * H + S[o];
  }
}

__global__ __launch_bounds__(256) void scan_pass2(
    const float* __restrict__ dt, const float* __restrict__ u,
    const float* __restrict__ bcdt, const float* __restrict__ logA,
    const float* __restrict__ Dp, const float* __restrict__ Hinit,
    const float* __restrict__ resu0, ushort* __restrict__ y2b)
{
  const int tid = threadIdx.x;
  const int n = tid & 15, dl = tid >> 4;
  const int dbase = blockIdx.x * 16;
  const int c = blockIdx.y;
  const int t0 = c * CLEN;
  const int d = dbase + dl;
  const float Aval = -expf(logA[d * DSTATE + n]);
  const float Dpv = Dp[d];
  __shared__ float sdt[CLEN][16], su[CLEN][16], sB[CLEN][16], sC[CLEN][16], sres[CLEN][16];
  {
    int tt = tid >> 2, j0 = (tid & 3) * 4;
    *(float4*)&sdt[tt][j0]  = *(const float4*)&dt[(size_t)(t0 + tt) * DINNER + dbase + j0];
    *(float4*)&su[tt][j0]   = *(const float4*)&u[(size_t)(t0 + tt) * DINNER + dbase + j0];
    *(float4*)&sB[tt][j0]   = *(const float4*)&bcdt[(size_t)(t0 + tt) * 96 + j0];
    *(float4*)&sC[tt][j0]   = *(const float4*)&bcdt[(size_t)(t0 + tt) * 96 + 16 + j0];
    *(float4*)&sres[tt][j0] = *(const float4*)&resu0[(size_t)(t0 + tt) * (2 * DINNER) + dbase + j0];
  }
  __syncthreads();
  float h = Hinit[(size_t)c * (DINNER * DSTATE) + (size_t)d * DSTATE + n];
#pragma unroll 4
  for (int i = 0; i < CLEN; ++i) {
    float dtv = sdt[i][dl], uv = su[i][dl];
    float dtA = dtv * Aval;
    float rinv = __builtin_amdgcn_rcpf(1.f - 0.5f * dtA);
    float dA = (1.f + 0.5f * dtA) * rinv;
    float dBu = dtv * sB[i][n] * rinv * uv;
    h = dA * h + dBu;
    float p = h * sC[i][n];
    p += __shfl_xor(p, 1);
    p += __shfl_xor(p, 2);
    p += __shfl_xor(p, 4);
    p += __shfl_xor(p, 8);
    if (n == 0) {
      float rv = sres[i][dl];
      float yv = (p + uv * Dpv) * (rv / (1.f + expf(-rv)));
      y2b[(size_t)(t0 + i) * DINNER + d] = f2bf(yv);
    }
  }
}

// ---------------- f32 -> bf16 cast ------------------------------------------
__global__ __launch_bounds__(256) void cast_bf16_kernel(
    const float* __restrict__ in, ushort* __restrict__ out, size_t n4)
{
  size_t i = (size_t)blockIdx.x * 256 + threadIdx.x;
  if (i >= n4) return;
  float4 v = ((const float4*)in)[i];
  ushort4 o = {f2bf(v.x), f2bf(v.y), f2bf(v.z), f2bf(v.w)};
  ((ushort4*)out)[i] = o;
}

// ---------------- concat-cast Wres|Win -> bf16 [L][2*DINNER][DMODEL] --------
__global__ __launch_bounds__(256) void cast_cat2_kernel(
    const float* __restrict__ Wres, const float* __restrict__ Win, ushort* __restrict__ out)
{
  size_t i4 = (size_t)blockIdx.x * 256 + threadIdx.x;
  size_t e0 = i4 * 4;
  int k = (int)(e0 & (DMODEL - 1));
  int r = (int)((e0 >> 10) & (2 * DINNER - 1));
  int l = (int)(e0 >> 22);
  const float* src = (r < DINNER)
      ? &Wres[(((size_t)l * DINNER + r) << 10) + k]
      : &Win[(((size_t)l * DINNER + (r - DINNER)) << 10) + k];
  float4 v = *(const float4*)src;
  ushort4 o = {f2bf(v.x), f2bf(v.y), f2bf(v.z), f2bf(v.w)};
  ((ushort4*)out)[i4] = o;
}

// ---------------- concat WB|WC|Wdt1 -> [L][96][DINNER] ----------------------
__global__ __launch_bounds__(256) void concat_wbcdt_kernel(
    const float* __restrict__ WB, const float* __restrict__ WC,
    const float* __restrict__ Wdt1, float* __restrict__ out)
{
  size_t idx = (size_t)blockIdx.x * 256 + threadIdx.x;
  int k = idx & (DINNER - 1);
  size_t rl = idx >> 11;
  int row = (int)(rl % 96);
  int l = (int)(rl / 96);
  float v;
  if (row < 16)       v = WB[((size_t)l * DSTATE + row) * DINNER + k];
  else if (row < 32)  v = WC[((size_t)l * DSTATE + (row - 16)) * DINNER + k];
  else                v = Wdt1[((size_t)l * DTRANK + (row - 32)) * DINNER + k];
  out[idx] = v;
}

// ============================================================================
extern "C" void kernel_launch(void* const* d_in, const int* in_sizes, int n_in,
                              void* d_out, int out_size, void* d_ws, size_t ws_size,
                              hipStream_t stream) {
  (void)in_sizes; (void)n_in; (void)out_size;
  const int* token_ids = (const int*)d_in[0];
  const float* embed = (const float*)d_in[1];
  const float* Wres = (const float*)d_in[2];
  const float* Win = (const float*)d_in[3];
  const float* Wconv = (const float*)d_in[4];
  const float* WB = (const float*)d_in[5];
  const float* WC = (const float*)d_in[6];
  const float* Wdt1 = (const float*)d_in[7];
  const float* Wdt2 = (const float*)d_in[8];
  const float* bdt = (const float*)d_in[9];
  const float* logA = (const float*)d_in[10];
  const float* Dp = (const float*)d_in[11];
  const float* Wout = (const float*)d_in[12];
  float* out = (float*)d_out;

  char* w = (char*)d_ws;
  auto alloc = [&](size_t bytes) {
    char* p = w;
    w += (bytes + 255) & ~(size_t)255;
    return p;
  };
  ushort* eb    = (ushort*)alloc((size_t)VOCAB * DMODEL * 2);
  ushort* wcatb = (ushort*)alloc((size_t)NLAYER * 2 * DINNER * DMODEL * 2);
  ushort* woutb = (ushort*)alloc((size_t)NLAYER * DMODEL * DINNER * 2);
  float* wbcdt  = (float*)alloc((size_t)NLAYER * 96 * DINNER * 4);
  float* x      = (float*)alloc((size_t)SEQ * DMODEL * 4);
  ushort* xnb   = (ushort*)alloc((size_t)SEQ * DMODEL * 2);
  float* resu0  = (float*)alloc((size_t)SEQ * 2 * DINNER * 4);
  float* u      = (float*)alloc((size_t)SEQ * DINNER * 4);
  float* bcdt   = (float*)alloc((size_t)SEQ * 96 * 4);
  float* dt     = (float*)alloc((size_t)SEQ * DINNER * 4);
  float* Cp     = (float*)alloc((size_t)PROJ_NCH * SEQ * 96 * 4);
  float* Pbuf   = (float*)alloc((size_t)NCHUNK * DINNER * DSTATE * 4);
  float* Sbuf   = (float*)alloc((size_t)NCHUNK * DINNER * DSTATE * 4);
  float* Hinit  = (float*)alloc((size_t)NCHUNK * DINNER * DSTATE * 4);
  ushort* y2b   = (ushort*)alloc((size_t)SEQ * DINNER * 2);
  ushort* xb    = (ushort*)alloc((size_t)SEQ * DMODEL * 2);
  if ((size_t)(w - (char*)d_ws) > ws_size) return;

  // weight preprocessing
  cast_bf16_kernel<<<VOCAB * DMODEL / 4 / 256, 256, 0, stream>>>(embed, eb, (size_t)VOCAB * DMODEL / 4);
  cast_cat2_kernel<<<NLAYER * 2 * DINNER * DMODEL / 4 / 256, 256, 0, stream>>>(Wres, Win, wcatb);
  cast_bf16_kernel<<<NLAYER * DMODEL * DINNER / 4 / 256, 256, 0, stream>>>(Wout, woutb, (size_t)NLAYER * DMODEL * DINNER / 4);
  concat_wbcdt_kernel<<<NLAYER * 96 * DINNER / 256, 256, 0, stream>>>(WB, WC, Wdt1, wbcdt);
  gather_kernel<<<SEQ, 256, 0, stream>>>(token_ids, embed, x);

  for (int i = 0; i < NLAYER; ++i) {
    const ushort* wcati = wcatb + (size_t)i * 2 * DINNER * DMODEL;
    const ushort* wouti = woutb + (size_t)i * DMODEL * DINNER;
    const float* wconvi = Wconv + (size_t)i * DINNER * 4;
    const float* wbcdti = wbcdt + (size_t)i * 96 * DINNER;
    const float* wdt2i = Wdt2 + (size_t)i * DINNER * DTRANK;
    const float* bdti = bdt + (size_t)i * DINNER;
    const float* logAi = logA + (size_t)i * DINNER * DSTATE;
    const float* Dpi = Dp + (size_t)i * DINNER;

    rmsnorm_kernel<<<SEQ, 256, 0, stream>>>(x, xnb);
    dim3 g1(SEQ / 128, 2 * DINNER / 128);
    gemm_bt_bf16<<<g1, 256, 0, stream>>>(xnb, wcati, nullptr, resu0, SEQ, 2 * DINNER, DMODEL);
    conv_silu_kernel<<<SEQ * DINNER / 4 / 256, 256, 0, stream>>>(resu0 + DINNER, 2 * DINNER, wconvi, u);
    projgemm_f32<<<dim3(SEQ / 64, PROJ_NCH), 256, 0, stream>>>(u, wbcdti, Cp, SEQ);
    proj_reduce<<<SEQ * 96 / 256, 256, 0, stream>>>(Cp, bcdt, SEQ);
    smallgemm_f32<<<dim3(SEQ / 64, DINNER / 64), 256, 0, stream>>>(
        bcdt + 32, 96, wdt2i, DTRANK, dt, DINNER, bdti, SEQ, DINNER, DTRANK, 1);
    dim3 gs(DINNER / 16, NCHUNK);
    scan_pass1<<<gs, 256, 0, stream>>>(dt, u, bcdt, logAi, Pbuf, Sbuf);
    scan_combine<<<DINNER * DSTATE / 256, 256, 0, stream>>>(Pbuf, Sbuf, Hinit);
    scan_pass2<<<gs, 256, 0, stream>>>(dt, u, bcdt, logAi, Dpi, Hinit, resu0, y2b);
    dim3 g2(SEQ / 128, DMODEL / 128);
    gemm_bt_bf16<<<g2, 256, 0, stream>>>(y2b, wouti, x, x, SEQ, DMODEL, DINNER);
  }
  cast_bf16_kernel<<<SEQ * DMODEL / 4 / 256, 256, 0, stream>>>(x, xb, (size_t)SEQ * DMODEL / 4);
  dim3 g3(SEQ / 128, VOCAB / 128);
  gemm_bt_bf16<<<g3, 256, 0, stream>>>(xb, eb, nullptr, out, SEQ, VOCAB, DMODEL);
}

// Round 4
// 2575.229 us; speedup vs baseline: 3.1021x; 1.0195x over previous
//
#include <hip/hip_runtime.h>

#define SEQ 2048
#define DMODEL 1024
#define DINNER 2048
#define DSTATE 16
#define DTRANK 64
#define NLAYER 8
#define VOCAB 32000
#define NCHUNK 32
#define CLEN 64   // SEQ / NCHUNK
#define PROJ_NCH 16
#define PROJ_KC 128  // DINNER / PROJ_NCH

typedef float f32x4 __attribute__((ext_vector_type(4)));
typedef short bf16x8 __attribute__((ext_vector_type(8)));

__device__ __forceinline__ ushort f2bf(float f) {
  union { float f; unsigned u; } v; v.f = f;
  unsigned r = v.u + 0x7fffu + ((v.u >> 16) & 1u);
  return (ushort)(r >> 16);
}

__device__ __forceinline__ void lds_load16(const void* g, void* l) {
  __builtin_amdgcn_global_load_lds(
      (const __attribute__((address_space(1))) void*)g,
      (__attribute__((address_space(3))) void*)l, 16, 0, 0);
}

// ---------------- 8-phase counted-vmcnt MFMA GEMM (T2+T3+T4+T5) -------------
// C[M,N] = A[M,K] @ B[N,K]^T.  BN=256 fixed, BM template (256 or 128).
// 512 threads = 8 waves (2 x 4); per-wave output BM/2 x 64.
// LDS XOR-swizzle: granule ^= (row&7), applied to global SOURCE at stage time
// (linear global_load_lds dest) and to the ds_read address (involution).
template<int BM>
__global__ __launch_bounds__(512, 2) void gemm8p_bt_bf16(
    const ushort* __restrict__ A, const ushort* __restrict__ B,
    float* __restrict__ C, int N, int K)
{
  constexpr int MFR = BM / 32;       // m-fragments per wave
  constexpr int MPP = MFR / 4;       // m-fragments per phase
  constexpr int ALOADS = BM / 128;   // global_load_lds per thread per A-half
  __shared__ __align__(16) ushort As[2 * BM * 64];
  __shared__ __align__(16) ushort Bs[2 * 256 * 64];
  const int tid = threadIdx.x;
  const int lane = tid & 63;
  const int wid = tid >> 6;
  const int wr = wid >> 2, wc = wid & 3;
  const int rr = lane & 15, kq = lane >> 4;

  unsigned nwg = gridDim.x * gridDim.y;
  unsigned lb = blockIdx.y * gridDim.x + blockIdx.x;
  if ((nwg & 7u) == 0u) { unsigned cpx = nwg >> 3; lb = (lb & 7u) * cpx + (lb >> 3); }
  const int bm = (int)(lb % gridDim.x) * BM;
  const int bn = (int)(lb / gridDim.x) * 256;

  const ushort* Abase = A + (size_t)bm * K;
  const ushort* Bbase = B + (size_t)bn * K;

  auto stageA = [&](int buf, int h, int kt) {
    constexpr int HR = BM / 2;
#pragma unroll
    for (int L = 0; L < ALOADS; ++L) {
      int f = L * 512 + tid;
      int rl = f >> 3, g = f & 7;
      int gg = g ^ (rl & 7);  // pre-swizzled source granule
      lds_load16(Abase + (size_t)(h * HR + rl) * K + kt * 64 + gg * 8,
                 (void*)(As + buf * (BM * 64) + (h * HR + rl) * 64 + g * 8));
    }
  };
  auto stageB = [&](int buf, int h, int kt) {
#pragma unroll
    for (int L = 0; L < 2; ++L) {
      int f = L * 512 + tid;
      int rl = f >> 3, g = f & 7;
      int gg = g ^ (rl & 7);
      lds_load16(Bbase + (size_t)(h * 128 + rl) * K + kt * 64 + gg * 8,
                 (void*)(Bs + buf * (256 * 64) + (h * 128 + rl) * 64 + g * 8));
    }
  };
  auto rdA = [&](int buf, int r, int kbyte) {
    int sw = kbyte ^ ((r & 7) << 4);
    return *(const bf16x8*)(As + buf * (BM * 64) + r * 64 + (sw >> 1));
  };
  auto rdB = [&](int buf, int r, int kbyte) {
    int sw = kbyte ^ ((r & 7) << 4);
    return *(const bf16x8*)(Bs + buf * (256 * 64) + r * 64 + (sw >> 1));
  };

  f32x4 acc[MFR][4];
#pragma unroll
  for (int m = 0; m < MFR; ++m)
#pragma unroll
    for (int n = 0; n < 4; ++n) acc[m][n] = (f32x4){0.f, 0.f, 0.f, 0.f};

  const int NT = K >> 6;
  stageA(0, 0, 0); stageA(0, 1, 0); stageB(0, 0, 0); stageB(0, 1, 0);

  for (int t = 0; t < NT; ++t) {
    const int cur = t & 1;
    const bool more = (t + 1 < NT);
    if (more) stageA(cur ^ 1, 0, t + 1);
    if (more) {
      if constexpr (BM == 256) asm volatile("s_waitcnt vmcnt(2)" ::: "memory");
      else                     asm volatile("s_waitcnt vmcnt(1)" ::: "memory");
    } else {
      asm volatile("s_waitcnt vmcnt(0)" ::: "memory");
    }
    __syncthreads();

    bf16x8 bfr[4][2];
#pragma unroll
    for (int n = 0; n < 4; ++n)
#pragma unroll
      for (int kk = 0; kk < 2; ++kk)
        bfr[n][kk] = rdB(cur, wc * 64 + n * 16 + rr, kk * 64 + kq * 16);

#pragma unroll
    for (int mq = 0; mq < 4; ++mq) {
      if (mq == 1 && more) stageA(cur ^ 1, 1, t + 1);
      if (mq == 2 && more) stageB(cur ^ 1, 0, t + 1);
      if (mq == 3 && more) stageB(cur ^ 1, 1, t + 1);
      bf16x8 af[MPP][2];
#pragma unroll
      for (int mf = 0; mf < MPP; ++mf)
#pragma unroll
        for (int kk = 0; kk < 2; ++kk)
          af[mf][kk] = rdA(cur, wr * (BM / 2) + (mq * MPP + mf) * 16 + rr, kk * 64 + kq * 16);
      __builtin_amdgcn_s_setprio(1);
#pragma unroll
      for (int kk = 0; kk < 2; ++kk)
#pragma unroll
        for (int mf = 0; mf < MPP; ++mf)
#pragma unroll
          for (int n = 0; n < 4; ++n)
            acc[mq * MPP + mf][n] = __builtin_amdgcn_mfma_f32_16x16x32_bf16(
                af[mf][kk], bfr[n][kk], acc[mq * MPP + mf][n], 0, 0, 0);
      __builtin_amdgcn_s_setprio(0);
    }
    __syncthreads();
  }

#pragma unroll
  for (int m = 0; m < MFR; ++m) {
    const int r0 = bm + wr * (BM / 2) + m * 16 + kq * 4;
#pragma unroll
    for (int n = 0; n < 4; ++n) {
      const int cc = bn + wc * 64 + n * 16 + rr;
#pragma unroll
      for (int j = 0; j < 4; ++j)
        C[(size_t)(r0 + j) * N + cc] = acc[m][n][j];
    }
  }
}

// ---------------- bf16 MFMA GEMM (2-phase 128x128), keeps fused addsrc ------
__global__ __launch_bounds__(256) void gemm_bt_bf16(
    const ushort* __restrict__ A, const ushort* __restrict__ B,
    const float* __restrict__ addsrc, float* __restrict__ C,
    int M, int N, int K)
{
  __shared__ __align__(16) ushort As[128 * 64];
  __shared__ __align__(16) ushort Bs[128 * 64];
  const int tid = threadIdx.x;
  const int lane = tid & 63;
  const int wave = tid >> 6;
  const int wr = wave >> 1, wc = wave & 1;

  unsigned nwg = gridDim.x * gridDim.y;
  unsigned lb = blockIdx.y * gridDim.x + blockIdx.x;
  if ((nwg & 7u) == 0u) {
    unsigned cpx = nwg >> 3;
    lb = (lb & 7u) * cpx + (lb >> 3);
  }
  const int bm = (lb % gridDim.x) * 128;
  const int bn = (lb / gridDim.x) * 128;
  const int rr = lane & 15, kq = lane >> 4;

  f32x4 acc[4][4];
#pragma unroll
  for (int m = 0; m < 4; ++m)
#pragma unroll
    for (int n = 0; n < 4; ++n) acc[m][n] = (f32x4){0.f, 0.f, 0.f, 0.f};

  for (int kt = 0; kt < K; kt += 64) {
#pragma unroll
    for (int i = 0; i < 4; ++i) {
      int fb = i * 256 + tid;
      int row = fb >> 3, cb = fb & 7;
      lds_load16(A + (size_t)(bm + row) * K + kt + cb * 8, (void*)(As + (size_t)fb * 8));
      lds_load16(B + (size_t)(bn + row) * K + kt + cb * 8, (void*)(Bs + (size_t)fb * 8));
    }
    __syncthreads();
#pragma unroll
    for (int ks = 0; ks < 2; ++ks) {
      bf16x8 af[4], bfr[4];
      const int koff = ks * 32 + kq * 8;
#pragma unroll
      for (int m = 0; m < 4; ++m)
        af[m] = *(const bf16x8*)&As[(wr * 64 + m * 16 + rr) * 64 + koff];
#pragma unroll
      for (int n = 0; n < 4; ++n)
        bfr[n] = *(const bf16x8*)&Bs[(wc * 64 + n * 16 + rr) * 64 + koff];
#pragma unroll
      for (int m = 0; m < 4; ++m)
#pragma unroll
        for (int n = 0; n < 4; ++n)
          acc[m][n] = __builtin_amdgcn_mfma_f32_16x16x32_bf16(af[m], bfr[n], acc[m][n], 0, 0, 0);
    }
    __syncthreads();
  }
#pragma unroll
  for (int m = 0; m < 4; ++m) {
    const int r0 = bm + wr * 64 + m * 16 + kq * 4;
#pragma unroll
    for (int n = 0; n < 4; ++n) {
      const int cc = bn + wc * 64 + n * 16 + rr;
#pragma unroll
      for (int j = 0; j < 4; ++j) {
        size_t idx = (size_t)(r0 + j) * N + cc;
        float v = acc[m][n][j];
        if (addsrc) v += addsrc[idx];
        C[idx] = v;
      }
    }
  }
}

// ---------------- split-K f32 projection GEMM: Cp[ch] = A@W^T chunk ---------
__global__ __launch_bounds__(256) void projgemm_f32(
    const float* __restrict__ A, const float* __restrict__ W,
    float* __restrict__ Cp, int M)
{
  __shared__ float As[64][65];
  __shared__ float Ws[96][65];
  const int t = threadIdx.x;
  const int bm = blockIdx.x * 64;
  const int kc = blockIdx.y * PROJ_KC;
  const int ty = t >> 4, tx = t & 15;
  const int r0 = ty * 4, c0 = tx * 6;
  float acc[4][6] = {};
  for (int kt = 0; kt < PROJ_KC; kt += 64) {
#pragma unroll
    for (int i = 0; i < 4; ++i) {
      int e4 = i * 256 + t;
      int r = e4 >> 4, c4 = (e4 & 15) * 4;
      *(float4*)&As[r][c4] = *(const float4*)&A[(size_t)(bm + r) * DINNER + kc + kt + c4];
    }
#pragma unroll
    for (int i = 0; i < 6; ++i) {
      int e4 = i * 256 + t;
      int r = e4 >> 4, c4 = (e4 & 15) * 4;
      *(float4*)&Ws[r][c4] = *(const float4*)&W[(size_t)r * DINNER + kc + kt + c4];
    }
    __syncthreads();
#pragma unroll 4
    for (int kk = 0; kk < 64; ++kk) {
      float a0 = As[r0][kk], a1 = As[r0 + 1][kk], a2 = As[r0 + 2][kk], a3 = As[r0 + 3][kk];
      float w0 = Ws[c0][kk], w1 = Ws[c0 + 1][kk], w2 = Ws[c0 + 2][kk];
      float w3 = Ws[c0 + 3][kk], w4 = Ws[c0 + 4][kk], w5 = Ws[c0 + 5][kk];
      acc[0][0] += a0 * w0; acc[0][1] += a0 * w1; acc[0][2] += a0 * w2;
      acc[0][3] += a0 * w3; acc[0][4] += a0 * w4; acc[0][5] += a0 * w5;
      acc[1][0] += a1 * w0; acc[1][1] += a1 * w1; acc[1][2] += a1 * w2;
      acc[1][3] += a1 * w3; acc[1][4] += a1 * w4; acc[1][5] += a1 * w5;
      acc[2][0] += a2 * w0; acc[2][1] += a2 * w1; acc[2][2] += a2 * w2;
      acc[2][3] += a2 * w3; acc[2][4] += a2 * w4; acc[2][5] += a2 * w5;
      acc[3][0] += a3 * w0; acc[3][1] += a3 * w1; acc[3][2] += a3 * w2;
      acc[3][3] += a3 * w3; acc[3][4] += a3 * w4; acc[3][5] += a3 * w5;
    }
    __syncthreads();
  }
  float* cp = Cp + (size_t)blockIdx.y * M * 96;
#pragma unroll
  for (int i = 0; i < 4; ++i)
#pragma unroll
    for (int j = 0; j < 6; ++j)
      cp[(size_t)(bm + r0 + i) * 96 + c0 + j] = acc[i][j];
}

__global__ __launch_bounds__(256) void proj_reduce(
    const float* __restrict__ Cp, float* __restrict__ bcdt, int M)
{
  int idx = blockIdx.x * 256 + threadIdx.x;
  float s = 0.f;
#pragma unroll
  for (int c = 0; c < PROJ_NCH; ++c) s += Cp[(size_t)c * M * 96 + idx];
  bcdt[idx] = s;
}

// ---------------- f32 small GEMM: C[M,N] = A[M,K(lda)] @ W[N,K(ldw)]^T ------
__global__ __launch_bounds__(256) void smallgemm_f32(
    const float* __restrict__ A, int lda,
    const float* __restrict__ W, int ldw,
    float* __restrict__ C, int ldc,
    const float* __restrict__ bias,
    int M, int N, int K, int act)
{
  __shared__ float As[64][65];
  __shared__ float Ws[64][65];
  const int t = threadIdx.x;
  const int bm = blockIdx.x * 64, bn = blockIdx.y * 64;
  const int r0 = (t >> 4) * 4;
  const int c0 = (t & 15) * 4;
  float acc[4][4] = {};

  for (int kt = 0; kt < K; kt += 64) {
#pragma unroll
    for (int i = 0; i < 16; ++i) {
      int idx = i * 256 + t;
      int r = idx >> 6, c = idx & 63;
      As[r][c] = A[(size_t)(bm + r) * lda + kt + c];
      int wrow = bn + r;
      Ws[r][c] = (wrow < N) ? W[(size_t)wrow * ldw + kt + c] : 0.f;
    }
    __syncthreads();
#pragma unroll 8
    for (int kk = 0; kk < 64; ++kk) {
      float a0 = As[r0][kk], a1 = As[r0 + 1][kk], a2 = As[r0 + 2][kk], a3 = As[r0 + 3][kk];
      float w0 = Ws[c0][kk], w1 = Ws[c0 + 1][kk], w2 = Ws[c0 + 2][kk], w3 = Ws[c0 + 3][kk];
      acc[0][0] += a0 * w0; acc[0][1] += a0 * w1; acc[0][2] += a0 * w2; acc[0][3] += a0 * w3;
      acc[1][0] += a1 * w0; acc[1][1] += a1 * w1; acc[1][2] += a1 * w2; acc[1][3] += a1 * w3;
      acc[2][0] += a2 * w0; acc[2][1] += a2 * w1; acc[2][2] += a2 * w2; acc[2][3] += a2 * w3;
      acc[3][0] += a3 * w0; acc[3][1] += a3 * w1; acc[3][2] += a3 * w2; acc[3][3] += a3 * w3;
    }
    __syncthreads();
  }
#pragma unroll
  for (int i = 0; i < 4; ++i)
#pragma unroll
    for (int j = 0; j < 4; ++j) {
      int cc = bn + c0 + j;
      if (cc < N) {
        float v = acc[i][j];
        if (bias) v += bias[cc];
        if (act == 1) v = (v > 20.f) ? v : log1pf(expf(v));
        C[(size_t)(bm + r0 + i) * ldc + cc] = v;
      }
    }
}

// ---------------- embedding gather ------------------------------------------
__global__ __launch_bounds__(256) void gather_kernel(
    const int* __restrict__ ids, const float* __restrict__ embed, float* __restrict__ x)
{
  int row = blockIdx.x;
  int id = ids[row];
  ((float4*)x)[(size_t)row * (DMODEL / 4) + threadIdx.x] =
      ((const float4*)(embed + (size_t)id * DMODEL))[threadIdx.x];
}

// ---------------- RMSNorm (no scale) -> bf16 --------------------------------
__global__ __launch_bounds__(256) void rmsnorm_kernel(
    const float* __restrict__ x, ushort* __restrict__ xnb)
{
  int row = blockIdx.x;
  float4 v = ((const float4*)(x + (size_t)row * DMODEL))[threadIdx.x];
  float s = v.x * v.x + v.y * v.y + v.z * v.z + v.w * v.w;
#pragma unroll
  for (int o = 32; o > 0; o >>= 1) s += __shfl_down(s, o);
  __shared__ float ws[4];
  if ((threadIdx.x & 63) == 0) ws[threadIdx.x >> 6] = s;
  __syncthreads();
  float tot = ws[0] + ws[1] + ws[2] + ws[3];
  float sc = rsqrtf(tot * (1.0f / DMODEL) + 1e-6f);
  ushort4 o4 = {f2bf(v.x * sc), f2bf(v.y * sc), f2bf(v.z * sc), f2bf(v.w * sc)};
  ((ushort4*)xnb)[(size_t)row * (DMODEL / 4) + threadIdx.x] = o4;
}

// ---------------- causal depthwise conv (K=4) + SiLU ------------------------
__global__ __launch_bounds__(256) void conv_silu_kernel(
    const float* __restrict__ u0, int ld, const float* __restrict__ Wconv,
    float* __restrict__ u)
{
  int idx = blockIdx.x * 256 + threadIdx.x;
  int d4 = idx & (DINNER / 4 - 1);
  int l = idx >> 9;
  int d0 = d4 * 4;
  float wt[4][4];
#pragma unroll
  for (int j = 0; j < 4; ++j) {
    float4 tv = *(const float4*)&Wconv[(d0 + j) * 4];
    wt[j][0] = tv.x; wt[j][1] = tv.y; wt[j][2] = tv.z; wt[j][3] = tv.w;
  }
  float a[4] = {0.f, 0.f, 0.f, 0.f};
#pragma unroll
  for (int k = 0; k < 4; ++k) {
    int ls = l - 3 + k;
    if (ls >= 0) {
      float4 uv = *(const float4*)&u0[(size_t)ls * ld + d0];
      a[0] += uv.x * wt[0][k];
      a[1] += uv.y * wt[1][k];
      a[2] += uv.z * wt[2][k];
      a[3] += uv.w * wt[3][k];
    }
  }
  float4 r;
  r.x = a[0] / (1.f + expf(-a[0]));
  r.y = a[1] / (1.f + expf(-a[1]));
  r.z = a[2] / (1.f + expf(-a[2]));
  r.w = a[3] / (1.f + expf(-a[3]));
  *(float4*)&u[(size_t)l * DINNER + d0] = r;
}

// ---------------- chunk-parallel selective scan -----------------------------
__global__ __launch_bounds__(256) void scan_pass1(
    const float* __restrict__ dt, const float* __restrict__ u,
    const float* __restrict__ bcdt, const float* __restrict__ logA,
    float* __restrict__ P, float* __restrict__ S)
{
  const int tid = threadIdx.x;
  const int n = tid & 15, dl = tid >> 4;
  const int dbase = blockIdx.x * 16;
  const int c = blockIdx.y;
  const int t0 = c * CLEN;
  const int d = dbase + dl;
  const float Aval = -expf(logA[d * DSTATE + n]);
  __shared__ float sdt[CLEN][16], su[CLEN][16], sB[CLEN][16];
  {
    int tt = tid >> 2, j0 = (tid & 3) * 4;
    *(float4*)&sdt[tt][j0] = *(const float4*)&dt[(size_t)(t0 + tt) * DINNER + dbase + j0];
    *(float4*)&su[tt][j0]  = *(const float4*)&u[(size_t)(t0 + tt) * DINNER + dbase + j0];
    *(float4*)&sB[tt][j0]  = *(const float4*)&bcdt[(size_t)(t0 + tt) * 96 + j0];
  }
  __syncthreads();
  float h = 0.f, pr = 1.f;
#pragma unroll 8
  for (int i = 0; i < CLEN; ++i) {
    float dtv = sdt[i][dl], uv = su[i][dl], Bv = sB[i][n];
    float dtA = dtv * Aval;
    float rinv = __builtin_amdgcn_rcpf(1.f - 0.5f * dtA);
    float dA = (1.f + 0.5f * dtA) * rinv;
    float dBu = dtv * Bv * rinv * uv;
    h = dA * h + dBu;
    pr *= dA;
  }
  size_t idx = (size_t)c * (DINNER * DSTATE) + (size_t)d * DSTATE + n;
  P[idx] = pr;
  S[idx] = h;
}

__global__ __launch_bounds__(256) void scan_combine(
    const float* __restrict__ P, const float* __restrict__ S, float* __restrict__ Hinit)
{
  int idx = blockIdx.x * 256 + threadIdx.x;
  float H = 0.f;
#pragma unroll
  for (int c = 0; c < NCHUNK; ++c) {
    size_t o = (size_t)c * (DINNER * DSTATE) + idx;
    Hinit[o] = H;
    H = P[o] * H + S[o];
  }
}

__global__ __launch_bounds__(256) void scan_pass2(
    const float* __restrict__ dt, const float* __restrict__ u,
    const float* __restrict__ bcdt, const float* __restrict__ logA,
    const float* __restrict__ Dp, const float* __restrict__ Hinit,
    const float* __restrict__ resu0, ushort* __restrict__ y2b)
{
  const int tid = threadIdx.x;
  const int n = tid & 15, dl = tid >> 4;
  const int dbase = blockIdx.x * 16;
  const int c = blockIdx.y;
  const int t0 = c * CLEN;
  const int d = dbase + dl;
  const float Aval = -expf(logA[d * DSTATE + n]);
  const float Dpv = Dp[d];
  __shared__ float sdt[CLEN][16], su[CLEN][16], sB[CLEN][16], sC[CLEN][16], sres[CLEN][16];
  {
    int tt = tid >> 2, j0 = (tid & 3) * 4;
    *(float4*)&sdt[tt][j0]  = *(const float4*)&dt[(size_t)(t0 + tt) * DINNER + dbase + j0];
    *(float4*)&su[tt][j0]   = *(const float4*)&u[(size_t)(t0 + tt) * DINNER + dbase + j0];
    *(float4*)&sB[tt][j0]   = *(const float4*)&bcdt[(size_t)(t0 + tt) * 96 + j0];
    *(float4*)&sC[tt][j0]   = *(const float4*)&bcdt[(size_t)(t0 + tt) * 96 + 16 + j0];
    *(float4*)&sres[tt][j0] = *(const float4*)&resu0[(size_t)(t0 + tt) * (2 * DINNER) + dbase + j0];
  }
  __syncthreads();
  float h = Hinit[(size_t)c * (DINNER * DSTATE) + (size_t)d * DSTATE + n];
#pragma unroll 4
  for (int i = 0; i < CLEN; ++i) {
    float dtv = sdt[i][dl], uv = su[i][dl];
    float dtA = dtv * Aval;
    float rinv = __builtin_amdgcn_rcpf(1.f - 0.5f * dtA);
    float dA = (1.f + 0.5f * dtA) * rinv;
    float dBu = dtv * sB[i][n] * rinv * uv;
    h = dA * h + dBu;
    float p = h * sC[i][n];
    p += __shfl_xor(p, 1);
    p += __shfl_xor(p, 2);
    p += __shfl_xor(p, 4);
    p += __shfl_xor(p, 8);
    if (n == 0) {
      float rv = sres[i][dl];
      float yv = (p + uv * Dpv) * (rv / (1.f + expf(-rv)));
      y2b[(size_t)(t0 + i) * DINNER + d] = f2bf(yv);
    }
  }
}

// ---------------- f32 -> bf16 cast ------------------------------------------
__global__ __launch_bounds__(256) void cast_bf16_kernel(
    const float* __restrict__ in, ushort* __restrict__ out, size_t n4)
{
  size_t i = (size_t)blockIdx.x * 256 + threadIdx.x;
  if (i >= n4) return;
  float4 v = ((const float4*)in)[i];
  ushort4 o = {f2bf(v.x), f2bf(v.y), f2bf(v.z), f2bf(v.w)};
  ((ushort4*)out)[i] = o;
}

// ---------------- concat-cast Wres|Win -> bf16 [L][2*DINNER][DMODEL] --------
__global__ __launch_bounds__(256) void cast_cat2_kernel(
    const float* __restrict__ Wres, const float* __restrict__ Win, ushort* __restrict__ out)
{
  size_t i4 = (size_t)blockIdx.x * 256 + threadIdx.x;
  size_t e0 = i4 * 4;
  int k = (int)(e0 & (DMODEL - 1));
  int r = (int)((e0 >> 10) & (2 * DINNER - 1));
  int l = (int)(e0 >> 22);
  const float* src = (r < DINNER)
      ? &Wres[(((size_t)l * DINNER + r) << 10) + k]
      : &Win[(((size_t)l * DINNER + (r - DINNER)) << 10) + k];
  float4 v = *(const float4*)src;
  ushort4 o = {f2bf(v.x), f2bf(v.y), f2bf(v.z), f2bf(v.w)};
  ((ushort4*)out)[i4] = o;
}

// ---------------- concat WB|WC|Wdt1 -> [L][96][DINNER] ----------------------
__global__ __launch_bounds__(256) void concat_wbcdt_kernel(
    const float* __restrict__ WB, const float* __restrict__ WC,
    const float* __restrict__ Wdt1, float* __restrict__ out)
{
  size_t idx = (size_t)blockIdx.x * 256 + threadIdx.x;
  int k = idx & (DINNER - 1);
  size_t rl = idx >> 11;
  int row = (int)(rl % 96);
  int l = (int)(rl / 96);
  float v;
  if (row < 16)       v = WB[((size_t)l * DSTATE + row) * DINNER + k];
  else if (row < 32)  v = WC[((size_t)l * DSTATE + (row - 16)) * DINNER + k];
  else                v = Wdt1[((size_t)l * DTRANK + (row - 32)) * DINNER + k];
  out[idx] = v;
}

// ============================================================================
extern "C" void kernel_launch(void* const* d_in, const int* in_sizes, int n_in,
                              void* d_out, int out_size, void* d_ws, size_t ws_size,
                              hipStream_t stream) {
  (void)in_sizes; (void)n_in; (void)out_size;
  const int* token_ids = (const int*)d_in[0];
  const float* embed = (const float*)d_in[1];
  const float* Wres = (const float*)d_in[2];
  const float* Win = (const float*)d_in[3];
  const float* Wconv = (const float*)d_in[4];
  const float* WB = (const float*)d_in[5];
  const float* WC = (const float*)d_in[6];
  const float* Wdt1 = (const float*)d_in[7];
  const float* Wdt2 = (const float*)d_in[8];
  const float* bdt = (const float*)d_in[9];
  const float* logA = (const float*)d_in[10];
  const float* Dp = (const float*)d_in[11];
  const float* Wout = (const float*)d_in[12];
  float* out = (float*)d_out;

  char* w = (char*)d_ws;
  auto alloc = [&](size_t bytes) {
    char* p = w;
    w += (bytes + 255) & ~(size_t)255;
    return p;
  };
  ushort* eb    = (ushort*)alloc((size_t)VOCAB * DMODEL * 2);
  ushort* wcatb = (ushort*)alloc((size_t)NLAYER * 2 * DINNER * DMODEL * 2);
  ushort* woutb = (ushort*)alloc((size_t)NLAYER * DMODEL * DINNER * 2);
  float* wbcdt  = (float*)alloc((size_t)NLAYER * 96 * DINNER * 4);
  float* x      = (float*)alloc((size_t)SEQ * DMODEL * 4);
  ushort* xnb   = (ushort*)alloc((size_t)SEQ * DMODEL * 2);
  float* resu0  = (float*)alloc((size_t)SEQ * 2 * DINNER * 4);
  float* u      = (float*)alloc((size_t)SEQ * DINNER * 4);
  float* bcdt   = (float*)alloc((size_t)SEQ * 96 * 4);
  float* dt     = (float*)alloc((size_t)SEQ * DINNER * 4);
  float* Cp     = (float*)alloc((size_t)PROJ_NCH * SEQ * 96 * 4);
  float* Pbuf   = (float*)alloc((size_t)NCHUNK * DINNER * DSTATE * 4);
  float* Sbuf   = (float*)alloc((size_t)NCHUNK * DINNER * DSTATE * 4);
  float* Hinit  = (float*)alloc((size_t)NCHUNK * DINNER * DSTATE * 4);
  ushort* y2b   = (ushort*)alloc((size_t)SEQ * DINNER * 2);
  ushort* xb    = (ushort*)alloc((size_t)SEQ * DMODEL * 2);
  if ((size_t)(w - (char*)d_ws) > ws_size) return;

  // weight preprocessing
  cast_bf16_kernel<<<VOCAB * DMODEL / 4 / 256, 256, 0, stream>>>(embed, eb, (size_t)VOCAB * DMODEL / 4);
  cast_cat2_kernel<<<NLAYER * 2 * DINNER * DMODEL / 4 / 256, 256, 0, stream>>>(Wres, Win, wcatb);
  cast_bf16_kernel<<<NLAYER * DMODEL * DINNER / 4 / 256, 256, 0, stream>>>(Wout, woutb, (size_t)NLAYER * DMODEL * DINNER / 4);
  concat_wbcdt_kernel<<<NLAYER * 96 * DINNER / 256, 256, 0, stream>>>(WB, WC, Wdt1, wbcdt);
  gather_kernel<<<SEQ, 256, 0, stream>>>(token_ids, embed, x);

  for (int i = 0; i < NLAYER; ++i) {
    const ushort* wcati = wcatb + (size_t)i * 2 * DINNER * DMODEL;
    const ushort* wouti = woutb + (size_t)i * DMODEL * DINNER;
    const float* wconvi = Wconv + (size_t)i * DINNER * 4;
    const float* wbcdti = wbcdt + (size_t)i * 96 * DINNER;
    const float* wdt2i = Wdt2 + (size_t)i * DINNER * DTRANK;
    const float* bdti = bdt + (size_t)i * DINNER;
    const float* logAi = logA + (size_t)i * DINNER * DSTATE;
    const float* Dpi = Dp + (size_t)i * DINNER;

    rmsnorm_kernel<<<SEQ, 256, 0, stream>>>(x, xnb);
    // 8-phase 128x256 GEMM: grid (2048/128, 4096/256) = (16,16) = 256 blocks
    gemm8p_bt_bf16<128><<<dim3(SEQ / 128, 2 * DINNER / 256), 512, 0, stream>>>(
        xnb, wcati, resu0, 2 * DINNER, DMODEL);
    conv_silu_kernel<<<SEQ * DINNER / 4 / 256, 256, 0, stream>>>(resu0 + DINNER, 2 * DINNER, wconvi, u);
    projgemm_f32<<<dim3(SEQ / 64, PROJ_NCH), 256, 0, stream>>>(u, wbcdti, Cp, SEQ);
    proj_reduce<<<SEQ * 96 / 256, 256, 0, stream>>>(Cp, bcdt, SEQ);
    smallgemm_f32<<<dim3(SEQ / 64, DINNER / 64), 256, 0, stream>>>(
        bcdt + 32, 96, wdt2i, DTRANK, dt, DINNER, bdti, SEQ, DINNER, DTRANK, 1);
    dim3 gs(DINNER / 16, NCHUNK);
    scan_pass1<<<gs, 256, 0, stream>>>(dt, u, bcdt, logAi, Pbuf, Sbuf);
    scan_combine<<<DINNER * DSTATE / 256, 256, 0, stream>>>(Pbuf, Sbuf, Hinit);
    scan_pass2<<<gs, 256, 0, stream>>>(dt, u, bcdt, logAi, Dpi, Hinit, resu0, y2b);
    dim3 g2(SEQ / 128, DMODEL / 128);
    gemm_bt_bf16<<<g2, 256, 0, stream>>>(y2b, wouti, x, x, SEQ, DMODEL, DINNER);
  }
  cast_bf16_kernel<<<SEQ * DMODEL / 4 / 256, 256, 0, stream>>>(x, xb, (size_t)SEQ * DMODEL / 4);
  // 8-phase 256x256 GEMM: grid (2048/256, 32000/256) = (8,125) = 1000 blocks
  gemm8p_bt_bf16<256><<<dim3(SEQ / 256, VOCAB / 256), 512, 0, stream>>>(
      xb, eb, out, VOCAB, DMODEL);
}